// Round 9
// baseline (2299.253 us; speedup 1.0000x reference)
//
#include <hip/hip_runtime.h>
#include <hip/hip_bf16.h>
#include <math.h>

using ull = unsigned long long;
typedef unsigned short u16x8 __attribute__((ext_vector_type(8)));
typedef __attribute__((ext_vector_type(8))) short bf16x8;   // 8 bf16 (4 VGPRs)
typedef __attribute__((ext_vector_type(4))) float f32x4;

// Problem constants
#define ND 4096ull   // n (xd rows)
#define NS 1024ull   // m (s1/s2 rows)
#define DOUT 256ull
#define DIN 768ull
#define NIT 36

// ---- u16 regions (ushort offsets into ws) ----
constexpr ull U_CXX = 0;                 // [ND*ND], shared by both divergences
constexpr ull U_CXY = U_CXX + ND*ND;     // [2][ND*NS]
constexpr ull U_CYX = U_CXY + 2*ND*NS;   // [2][NS*ND] transposed copies
constexpr ull U_CYY = U_CYX + 2*ND*NS;   // [2][NS*NS]
constexpr ull U_TOT = U_CYY + 2*NS*NS;   // ~71.3 MB
// bf16 hi/mid packed fragment buffers (ushort offsets)
constexpr ull P_XDH = U_TOT;
constexpr ull P_XDM = P_XDH + ND*DOUT;
constexpr ull P_X1H = P_XDM + ND*DOUT;
constexpr ull P_X1M = P_X1H + NS*DOUT;
constexpr ull P_X2H = P_X1M + NS*DOUT;
constexpr ull P_X2M = P_X2H + NS*DOUT;
constexpr ull U_END = P_X2M + NS*DOUT;   // even

// ---- fp32 region (float offsets into ws) ----
constexpr ull O_XD   = U_END / 2;
constexpr ull O_X1   = O_XD + ND*DOUT;
constexpr ull O_X2   = O_X1 + NS*DOUT;
constexpr ull O_MT   = O_X2 + NS*DOUT;       // [DOUT*DIN], dead after proj GEMMs
constexpr ull O_ND_  = O_MT + DOUT*DIN;
constexpr ull O_N1   = O_ND_ + ND;
constexpr ull O_N2   = O_N1 + NS;
constexpr ull O_FAB  = O_N2 + NS;            // [2 div][2 buf][ND]
constexpr ull O_GAB  = O_FAB + 4*ND;         // [2][2][NS]
constexpr ull O_FAA  = O_GAB + 4*NS;         // [2][2][ND]
constexpr ull O_GBB  = O_FAA + 4*ND;         // [2][2][NS]
constexpr ull O_FABN = O_GBB + 4*NS;         // [2][ND]
constexpr ull O_GABN = O_FABN + 2*ND;        // [2][NS]
constexpr ull O_FAAN = O_GABN + 2*NS;        // [2][ND]
constexpr ull O_GBBN = O_FAAN + 2*ND;        // [2][NS]
constexpr ull O_EPS  = O_GBBN + 2*NS;        // [2][NIT]
constexpr ull O_QS   = O_EPS + 2*NIT;        // [0]=quant scale, [1]=dequant
constexpr ull O_DIST = O_QS + 2;             // [2]
constexpr ull WS_FLOATS = O_DIST + 2;        // ~85 MB total
// diameter partials reuse dead Mt region
constexpr ull O_PMIN = O_MT;                 // [96*256]
constexpr ull O_PMAX = O_MT + 96*256;        // [96*256]

constexpr float LOG2E = 1.4426950408889634f;
constexpr float LN2   = 0.69314718055994531f;
constexpr float A_LOG2 = -12.0f;   // -log2(4096)
constexpr float B_LOG2 = -10.0f;   // -log2(1024)

__device__ __forceinline__ float wave_max(float v) {
    #pragma unroll
    for (int o = 32; o; o >>= 1) v = fmaxf(v, __shfl_xor(v, o));
    return v;
}
__device__ __forceinline__ float wave_sum(float v) {
    #pragma unroll
    for (int o = 32; o; o >>= 1) v += __shfl_xor(v, o);
    return v;
}

__device__ __forceinline__ unsigned short f2bf_rn(float x) {
    union { float f; unsigned u; } v; v.f = x;
    const unsigned r = v.u + 0x7FFFu + ((v.u >> 16) & 1u);
    return (unsigned short)(r >> 16);
}
__device__ __forceinline__ float bf2f(unsigned short b) {
    union { unsigned u; float f; } v; v.u = ((unsigned)b) << 16; return v.f;
}

// ---- transpose M [DIN x DOUT] -> Mt [DOUT x DIN] ----
__global__ __launch_bounds__(256)
void transpose_M_k(const float* __restrict__ M, float* __restrict__ Mt)
{
    int idx = blockIdx.x * 256 + threadIdx.x;
    int r = idx >> 8;
    int c = idx & 255;
    Mt[(size_t)c * DIN + r] = M[idx];
}

// ---- projection GEMM: P = A[MxK] @ B[NxK]^T (64x64 tile, 4x4/thread) ----
__global__ __launch_bounds__(256)
void gemm_proj(const float* __restrict__ A, const float* __restrict__ B,
               float* __restrict__ C, int M, int N, int K)
{
    __shared__ __align__(16) float As[16][68];
    __shared__ __align__(16) float Bs[16][68];
    const int m0 = blockIdx.y * 64, n0 = blockIdx.x * 64;
    const int t = threadIdx.x;
    const int lk = t & 15, lr = t >> 4;
    const int tm = t >> 4, tn = t & 15;
    float acc[4][4] = {};
    for (int k0 = 0; k0 < K; k0 += 16) {
        #pragma unroll
        for (int r = 0; r < 4; r++) {
            As[lk][lr + r*16] = A[(size_t)(m0 + lr + r*16) * K + (k0 + lk)];
            Bs[lk][lr + r*16] = B[(size_t)(n0 + lr + r*16) * K + (k0 + lk)];
        }
        __syncthreads();
        #pragma unroll
        for (int k = 0; k < 16; k++) {
            const float4 a4 = *(const float4*)&As[k][tm*4];
            const float4 b4 = *(const float4*)&Bs[k][tn*4];
            const float av[4] = {a4.x, a4.y, a4.z, a4.w};
            const float bv[4] = {b4.x, b4.y, b4.z, b4.w};
            #pragma unroll
            for (int i = 0; i < 4; i++)
                #pragma unroll
                for (int j = 0; j < 4; j++)
                    acc[i][j] = fmaf(av[i], bv[j], acc[i][j]);
        }
        __syncthreads();
    }
    #pragma unroll
    for (int i = 0; i < 4; i++)
        #pragma unroll
        for (int j = 0; j < 4; j++)
            C[(size_t)(m0 + tm*4 + i) * N + (n0 + tn*4 + j)] = acc[i][j];
}

// ---- pack fp32 [R][256] -> bf16 hi/mid in MFMA fragment order ----
// slot(p,kb,l,e) = ((p*8+kb)*64+l)*8+e  holds  X[p*16+(l&15)][kb*32+(l>>4)*8+e]
__global__ __launch_bounds__(256)
void pack_bf16_k(const float* __restrict__ X,
                 unsigned short* __restrict__ Phi, unsigned short* __restrict__ Pmi)
{
    const int p = blockIdx.x;
    const int t = threadIdx.x;
    #pragma unroll
    for (int s = t; s < 512; s += 256) {
        const int kb = s >> 6, l = s & 63;
        const int row = p * 16 + (l & 15);
        const int k0 = kb * 32 + ((l >> 4) << 3);
        const float* src = X + (ull)row * DOUT + k0;
        u16x8 hi, mi;
        #pragma unroll
        for (int e = 0; e < 8; e++) {
            const float x = src[e];
            const unsigned short h = f2bf_rn(x);
            hi[e] = h;
            mi[e] = f2bf_rn(x - bf2f(h));
        }
        const ull o = (((ull)p * 8 + kb) * 64 + l) * 8;
        *(u16x8*)&Phi[o] = hi;
        *(u16x8*)&Pmi[o] = mi;
    }
}

// ---- MFMA cost GEMM (bf16x3 split): C[i][j]=quant(0.5*max(na+nb-2*dot,0)) ----
__device__ __forceinline__ unsigned int quant16(float c, float s) {
    return __float2uint_rn(fminf(c * s, 65535.0f));
}

__global__ __launch_bounds__(256)
void gemm_cost_mfma(const unsigned short* __restrict__ Ahi, const unsigned short* __restrict__ Ami,
                    const unsigned short* __restrict__ Bhi, const unsigned short* __restrict__ Bmi,
                    unsigned short* __restrict__ C,
                    const float* __restrict__ na, const float* __restrict__ nb,
                    const float* __restrict__ qsp, int N)
{
    const int l = threadIdx.x & 63;
    const int w = threadIdx.x >> 6;
    const int n0 = blockIdx.x * 64, m0 = blockIdx.y * 64;
    const int pA = (m0 >> 4) + w;
    const int pB0 = n0 >> 4;
    f32x4 a0 = {}, a1 = {}, a2 = {}, a3 = {};
    #pragma unroll
    for (int kb = 0; kb < 8; kb++) {
        const ull ao = (((ull)pA * 8 + kb) * 64 + l) * 8;
        const bf16x8 aH = *(const bf16x8*)&Ahi[ao];
        const bf16x8 aM = *(const bf16x8*)&Ami[ao];
        const ull b0o = (((ull)(pB0 + 0) * 8 + kb) * 64 + l) * 8;
        const ull b1o = (((ull)(pB0 + 1) * 8 + kb) * 64 + l) * 8;
        const ull b2o = (((ull)(pB0 + 2) * 8 + kb) * 64 + l) * 8;
        const ull b3o = (((ull)(pB0 + 3) * 8 + kb) * 64 + l) * 8;
        bf16x8 bH, bM;
        bH = *(const bf16x8*)&Bhi[b0o]; bM = *(const bf16x8*)&Bmi[b0o];
        a0 = __builtin_amdgcn_mfma_f32_16x16x32_bf16(aH, bH, a0, 0, 0, 0);
        a0 = __builtin_amdgcn_mfma_f32_16x16x32_bf16(aH, bM, a0, 0, 0, 0);
        a0 = __builtin_amdgcn_mfma_f32_16x16x32_bf16(aM, bH, a0, 0, 0, 0);
        bH = *(const bf16x8*)&Bhi[b1o]; bM = *(const bf16x8*)&Bmi[b1o];
        a1 = __builtin_amdgcn_mfma_f32_16x16x32_bf16(aH, bH, a1, 0, 0, 0);
        a1 = __builtin_amdgcn_mfma_f32_16x16x32_bf16(aH, bM, a1, 0, 0, 0);
        a1 = __builtin_amdgcn_mfma_f32_16x16x32_bf16(aM, bH, a1, 0, 0, 0);
        bH = *(const bf16x8*)&Bhi[b2o]; bM = *(const bf16x8*)&Bmi[b2o];
        a2 = __builtin_amdgcn_mfma_f32_16x16x32_bf16(aH, bH, a2, 0, 0, 0);
        a2 = __builtin_amdgcn_mfma_f32_16x16x32_bf16(aH, bM, a2, 0, 0, 0);
        a2 = __builtin_amdgcn_mfma_f32_16x16x32_bf16(aM, bH, a2, 0, 0, 0);
        bH = *(const bf16x8*)&Bhi[b3o]; bM = *(const bf16x8*)&Bmi[b3o];
        a3 = __builtin_amdgcn_mfma_f32_16x16x32_bf16(aH, bH, a3, 0, 0, 0);
        a3 = __builtin_amdgcn_mfma_f32_16x16x32_bf16(aH, bM, a3, 0, 0, 0);
        a3 = __builtin_amdgcn_mfma_f32_16x16x32_bf16(aM, bH, a3, 0, 0, 0);
    }
    // C/D layout (m89-verified): col = lane&15, row = (lane>>4)*4 + reg
    const float s = qsp[0];
    const int row0 = m0 + w * 16 + ((l >> 4) << 2);
    const int col = l & 15;
    float nar[4];
    #pragma unroll
    for (int r = 0; r < 4; r++) nar[r] = na[row0 + r];
    const float nb0 = nb[n0 + col];
    const float nb1 = nb[n0 + 16 + col];
    const float nb2 = nb[n0 + 32 + col];
    const float nb3 = nb[n0 + 48 + col];
    #pragma unroll
    for (int r = 0; r < 4; r++) {
        const ull rowb = (ull)(row0 + r) * N + n0;
        C[rowb + col]      = (unsigned short)quant16(0.5f * fmaxf(nar[r] + nb0 - 2.0f * a0[r], 0.0f), s);
        C[rowb + 16 + col] = (unsigned short)quant16(0.5f * fmaxf(nar[r] + nb1 - 2.0f * a1[r], 0.0f), s);
        C[rowb + 32 + col] = (unsigned short)quant16(0.5f * fmaxf(nar[r] + nb2 - 2.0f * a2[r], 0.0f), s);
        C[rowb + 48 + col] = (unsigned short)quant16(0.5f * fmaxf(nar[r] + nb3 - 2.0f * a3[r], 0.0f), s);
    }
}

// ---- row squared-norms ----
__global__ __launch_bounds__(256)
void row_norm(const float* __restrict__ x, float* __restrict__ o)
{
    const int i = blockIdx.x;
    const float v = x[(size_t)i * DOUT + threadIdx.x];
    float s = wave_sum(v * v);
    __shared__ float red[4];
    const int wid = threadIdx.x >> 6, lane = threadIdx.x & 63;
    if (lane == 0) red[wid] = s;
    __syncthreads();
    if (threadIdx.x == 0) o[i] = red[0] + red[1] + red[2] + red[3];
}

// ---- per-column min/max partials ----
__global__ __launch_bounds__(256)
void colminmax_k(const float* __restrict__ xd, const float* __restrict__ x1,
                 const float* __restrict__ x2, float* __restrict__ ws)
{
    const int b = blockIdx.x, c = threadIdx.x;
    const float* src; int r0;
    if (b < 64)      { src = xd; r0 = b * 64; }
    else if (b < 80) { src = x1; r0 = (b - 64) * 64; }
    else             { src = x2; r0 = (b - 80) * 64; }
    float mn = 3.4e38f, mx = -3.4e38f;
    for (int r = 0; r < 64; r++) {
        const float v = src[(size_t)(r0 + r) * DOUT + c];
        mn = fminf(mn, v); mx = fmaxf(mx, v);
    }
    ws[O_PMIN + (ull)b * 256 + c] = mn;
    ws[O_PMAX + (ull)b * 256 + c] = mx;
}

// ---- partials -> diam -> eps schedule + quant scale ----
__global__ __launch_bounds__(256)
void eps_k(float* __restrict__ ws)
{
    const int c = threadIdx.x;
    const float* pmin = ws + O_PMIN;
    const float* pmax = ws + O_PMAX;
    float mnd = 3.4e38f, mxd = -3.4e38f;
    float mn1 = 3.4e38f, mx1 = -3.4e38f;
    float mn2 = 3.4e38f, mx2 = -3.4e38f;
    for (int b = 0;  b < 64; b++) { mnd = fminf(mnd, pmin[b*256+c]); mxd = fmaxf(mxd, pmax[b*256+c]); }
    for (int b = 64; b < 80; b++) { mn1 = fminf(mn1, pmin[b*256+c]); mx1 = fmaxf(mx1, pmax[b*256+c]); }
    for (int b = 80; b < 96; b++) { mn2 = fminf(mn2, pmin[b*256+c]); mx2 = fmaxf(mx2, pmax[b*256+c]); }
    const float d1 = fmaxf(mxd, mx1) - fminf(mnd, mn1);
    const float d2 = fmaxf(mxd, mx2) - fminf(mnd, mn2);
    float s1 = wave_sum(d1 * d1);
    float s2 = wave_sum(d2 * d2);
    __shared__ float r1[4], r2[4];
    const int wid = c >> 6, lane = c & 63;
    if (lane == 0) { r1[wid] = s1; r2[wid] = s2; }
    __syncthreads();
    if (c == 0) {
        const float d1s = r1[0]+r1[1]+r1[2]+r1[3];
        const float d2s = r2[0]+r2[1]+r2[2]+r2[3];
        const float cb = 0.5f * fmaxf(d1s, d2s) * 1.02f + 1.0f;
        ws[O_QS]     = 65535.0f / cb;
        ws[O_QS + 1] = cb / 65535.0f;
    }
    if (c < 2 * NIT) {
        const int div = c / NIT, tt = c % NIT;
        const float ss = div ? (r2[0]+r2[1]+r2[2]+r2[3]) : (r1[0]+r1[1]+r1[2]+r1[3]);
        const float diam = sqrtf(ss) + 1e-6f;
        const float sc = fmaxf(0.5f, diam * powf(0.8f, (float)tt));
        ws[O_EPS + (ull)div * NIT + tt] = sc * sc;
    }
}

__device__ __forceinline__ float tmax8(const float* v) {
    return fmaxf(fmaxf(fmaxf(v[0],v[1]),fmaxf(v[2],v[3])),
                 fmaxf(fmaxf(v[4],v[5]),fmaxf(v[6],v[7])));
}

// ---- flat softmin for short rows (NC chunks of 512; v kept in regs) ----
template<int NC>
__device__ __forceinline__ void softmin_flat(
    const unsigned short* __restrict__ Crow, const float* __restrict__ hvec,
    float hc2, float eps, float qs,
    const float* __restrict__ selfv, float* __restrict__ outp,
    int row, int phase, int lane)
{
    const float ie2 = LOG2E / eps;
    const float qsc = -qs * ie2;
    float v[NC * 8];
    #pragma unroll
    for (int c = 0; c < NC; c++) {
        const int off = c * 512 + lane * 8;
        const u16x8 q = *(const u16x8*)&Crow[off];
        if (hvec) {
            const float4 ha = *(const float4*)&hvec[off];
            const float4 hb = *(const float4*)&hvec[off + 4];
            const float hv[8] = {ha.x, ha.y, ha.z, ha.w, hb.x, hb.y, hb.z, hb.w};
            #pragma unroll
            for (int e = 0; e < 8; e++)
                v[c*8 + e] = fmaf((float)q[e], qsc, fmaf(hv[e], ie2, hc2));
        } else {
            #pragma unroll
            for (int e = 0; e < 8; e++)
                v[c*8 + e] = fmaf((float)q[e], qsc, hc2);
        }
    }
    float m = v[0];
    #pragma unroll
    for (int k = 1; k < NC * 8; k++) m = fmaxf(m, v[k]);
    m = wave_max(m);
    float sa[4] = {0.0f, 0.0f, 0.0f, 0.0f};
    #pragma unroll
    for (int k = 0; k < NC * 8; k++) sa[k & 3] += exp2f(v[k] - m);
    float s = wave_sum((sa[0] + sa[1]) + (sa[2] + sa[3]));
    if (lane == 0) {
        float res = -eps * LN2 * (m + log2f(s));
        if (phase == 1) res = 0.5f * (selfv[row] + res);
        outp[row] = res;
    }
}

// ---- online softmin for long rows (8 live values; low VGPR) ----
template<int NC>
__device__ __forceinline__ void softmin_online(
    const unsigned short* __restrict__ Crow, const float* __restrict__ hvec,
    float hc2, float eps, float qs,
    const float* __restrict__ selfv, float* __restrict__ outp,
    int row, int phase, int lane)
{
    const float ie2 = LOG2E / eps;
    const float qsc = -qs * ie2;
    float m = -1e30f, s = 0.0f;
    #pragma unroll
    for (int c = 0; c < NC; c++) {
        const int off = c * 512 + lane * 8;
        const u16x8 q = *(const u16x8*)&Crow[off];
        float v[8];
        if (hvec) {
            const float4 ha = *(const float4*)&hvec[off];
            const float4 hb = *(const float4*)&hvec[off + 4];
            v[0] = fmaf((float)q[0], qsc, fmaf(ha.x, ie2, hc2));
            v[1] = fmaf((float)q[1], qsc, fmaf(ha.y, ie2, hc2));
            v[2] = fmaf((float)q[2], qsc, fmaf(ha.z, ie2, hc2));
            v[3] = fmaf((float)q[3], qsc, fmaf(ha.w, ie2, hc2));
            v[4] = fmaf((float)q[4], qsc, fmaf(hb.x, ie2, hc2));
            v[5] = fmaf((float)q[5], qsc, fmaf(hb.y, ie2, hc2));
            v[6] = fmaf((float)q[6], qsc, fmaf(hb.z, ie2, hc2));
            v[7] = fmaf((float)q[7], qsc, fmaf(hb.w, ie2, hc2));
        } else {
            #pragma unroll
            for (int e = 0; e < 8; e++) v[e] = fmaf((float)q[e], qsc, hc2);
        }
        const float cm = tmax8(v);
        const float mn = fmaxf(m, cm);
        float p0 = exp2f(v[0]-mn) + exp2f(v[1]-mn);
        float p1 = exp2f(v[2]-mn) + exp2f(v[3]-mn);
        float p2 = exp2f(v[4]-mn) + exp2f(v[5]-mn);
        float p3 = exp2f(v[6]-mn) + exp2f(v[7]-mn);
        s = fmaf(s, exp2f(m - mn), (p0 + p1) + (p2 + p3));
        m = mn;
    }
    const float mt = wave_max(m);
    const float st = wave_sum(s * exp2f(m - mt));
    if (lane == 0) {
        float res = -eps * LN2 * (mt + log2f(st));
        if (phase == 1) res = 0.5f * (selfv[row] + res);
        outp[row] = res;
    }
}

// ---- faa: ONE online pass over a C_xx row, BOTH divergences (cvt once) ----
__device__ __forceinline__ void softmin_faa_online(
    const unsigned short* __restrict__ Crow,
    const float* __restrict__ h0, const float* __restrict__ h1,
    float eps0, float eps1, float qs,
    float* __restrict__ out0, float* __restrict__ out1,
    int row, int phase, int lane)
{
    const float ie0 = LOG2E / eps0, ie1 = LOG2E / eps1;
    const float qs0 = -qs * ie0, qs1 = -qs * ie1;
    float m0 = -1e30f, s0 = 0.0f, m1 = -1e30f, s1 = 0.0f;
    #pragma unroll
    for (int c = 0; c < 8; c++) {
        const int off = c * 512 + lane * 8;
        const u16x8 q = *(const u16x8*)&Crow[off];
        float cq[8];
        #pragma unroll
        for (int e = 0; e < 8; e++) cq[e] = (float)q[e];
        float v[8];
        // divergence 0
        if (phase) {
            const float4 a = *(const float4*)&h0[off];
            const float4 b = *(const float4*)&h0[off + 4];
            v[0] = fmaf(cq[0], qs0, fmaf(a.x, ie0, A_LOG2));
            v[1] = fmaf(cq[1], qs0, fmaf(a.y, ie0, A_LOG2));
            v[2] = fmaf(cq[2], qs0, fmaf(a.z, ie0, A_LOG2));
            v[3] = fmaf(cq[3], qs0, fmaf(a.w, ie0, A_LOG2));
            v[4] = fmaf(cq[4], qs0, fmaf(b.x, ie0, A_LOG2));
            v[5] = fmaf(cq[5], qs0, fmaf(b.y, ie0, A_LOG2));
            v[6] = fmaf(cq[6], qs0, fmaf(b.z, ie0, A_LOG2));
            v[7] = fmaf(cq[7], qs0, fmaf(b.w, ie0, A_LOG2));
        } else {
            #pragma unroll
            for (int e = 0; e < 8; e++) v[e] = fmaf(cq[e], qs0, A_LOG2);
        }
        {
            const float mn = fmaxf(m0, tmax8(v));
            float p0 = exp2f(v[0]-mn) + exp2f(v[1]-mn);
            float p1 = exp2f(v[2]-mn) + exp2f(v[3]-mn);
            float p2 = exp2f(v[4]-mn) + exp2f(v[5]-mn);
            float p3 = exp2f(v[6]-mn) + exp2f(v[7]-mn);
            s0 = fmaf(s0, exp2f(m0 - mn), (p0 + p1) + (p2 + p3));
            m0 = mn;
        }
        // divergence 1
        if (phase) {
            const float4 a = *(const float4*)&h1[off];
            const float4 b = *(const float4*)&h1[off + 4];
            v[0] = fmaf(cq[0], qs1, fmaf(a.x, ie1, A_LOG2));
            v[1] = fmaf(cq[1], qs1, fmaf(a.y, ie1, A_LOG2));
            v[2] = fmaf(cq[2], qs1, fmaf(a.z, ie1, A_LOG2));
            v[3] = fmaf(cq[3], qs1, fmaf(a.w, ie1, A_LOG2));
            v[4] = fmaf(cq[4], qs1, fmaf(b.x, ie1, A_LOG2));
            v[5] = fmaf(cq[5], qs1, fmaf(b.y, ie1, A_LOG2));
            v[6] = fmaf(cq[6], qs1, fmaf(b.z, ie1, A_LOG2));
            v[7] = fmaf(cq[7], qs1, fmaf(b.w, ie1, A_LOG2));
        } else {
            #pragma unroll
            for (int e = 0; e < 8; e++) v[e] = fmaf(cq[e], qs1, A_LOG2);
        }
        {
            const float mn = fmaxf(m1, tmax8(v));
            float p0 = exp2f(v[0]-mn) + exp2f(v[1]-mn);
            float p1 = exp2f(v[2]-mn) + exp2f(v[3]-mn);
            float p2 = exp2f(v[4]-mn) + exp2f(v[5]-mn);
            float p3 = exp2f(v[6]-mn) + exp2f(v[7]-mn);
            s1 = fmaf(s1, exp2f(m1 - mn), (p0 + p1) + (p2 + p3));
            m1 = mn;
        }
    }
    float mt = wave_max(m0);
    float st = wave_sum(s0 * exp2f(m0 - mt));
    if (lane == 0) {
        float res = -eps0 * LN2 * (mt + log2f(st));
        if (phase == 1) res = 0.5f * (h0[row] + res);   // h0 == faa_r0 (self)
        out0[row] = res;
    }
    mt = wave_max(m1);
    st = wave_sum(s1 * exp2f(m1 - mt));
    if (lane == 0) {
        float res = -eps1 * LN2 * (mt + log2f(st));
        if (phase == 1) res = 0.5f * (h1[row] + res);
        out1[row] = res;
    }
}

// ---- fused Sinkhorn step: 16384 waves (4096 blocks), low-VGPR softmins ----
//  [0,8192)      ft   (C_xy rows, len 1024), div = w>>12
//  [8192,10240)  gt   (C_yx rows, len 4096), div = (w-8192)>>10
//  [10240,14336) f_aa (C_xx rows), both divergences in ONE row pass
//  [14336,16384) g_bb (C_yy rows, len 1024), div = (w-14336)>>10
__global__ __launch_bounds__(256, 8)
void sinkhorn_phase(float* __restrict__ ws, int phase, int t)
{
    const unsigned short* uq = (const unsigned short*)ws;
    const int wid = threadIdx.x >> 6, lane = threadIdx.x & 63;
    const int w = blockIdx.x * 4 + wid;
    const float qs = ws[O_QS + 1];
    int rb, wb;
    if (phase == 0) { rb = 0; wb = 0; }
    else { rb = t & 1; wb = rb ^ 1; }   // phase 2 passes t=36 -> rb=0

    if (w < 8192) {                       // ft -> f_ab
        const int div = w >> 12, i = w & 4095;
        const float eps = (phase == 2) ? 0.25f : ws[O_EPS + (ull)div * NIT + t];
        const unsigned short* Crow = uq + U_CXY + (ull)div * ND * NS + (ull)i * NS;
        const float* gab_r = ws + O_GAB + ((ull)div * 2 + rb) * NS;
        const float* fab_r = ws + O_FAB + ((ull)div * 2 + rb) * ND;
        float* outp = (phase == 2) ? (ws + O_FABN + (ull)div * ND)
                                   : (ws + O_FAB + ((ull)div * 2 + wb) * ND);
        softmin_flat<2>(Crow, phase ? gab_r : nullptr, B_LOG2, eps, qs, fab_r, outp, i, phase, lane);
    } else if (w < 10240) {               // gt -> g_ab
        const int q = w - 8192, div = q >> 10, j = q & 1023;
        const float eps = (phase == 2) ? 0.25f : ws[O_EPS + (ull)div * NIT + t];
        const unsigned short* Crow = uq + U_CYX + (ull)div * ND * NS + (ull)j * ND;
        const float* fab_r = ws + O_FAB + ((ull)div * 2 + rb) * ND;
        const float* gab_r = ws + O_GAB + ((ull)div * 2 + rb) * NS;
        float* outp = (phase == 2) ? (ws + O_GABN + (ull)div * NS)
                                   : (ws + O_GAB + ((ull)div * 2 + wb) * NS);
        softmin_online<8>(Crow, phase ? fab_r : nullptr, A_LOG2, eps, qs, gab_r, outp, j, phase, lane);
    } else if (w < 14336) {               // f_aa, both divergences, one pass
        const int i = w - 10240;
        const float eps0 = (phase == 2) ? 0.25f : ws[O_EPS + t];
        const float eps1 = (phase == 2) ? 0.25f : ws[O_EPS + NIT + t];
        const unsigned short* Crow = uq + U_CXX + (ull)i * ND;
        const float* faa_r0 = ws + O_FAA + (ull)rb * ND;
        const float* faa_r1 = ws + O_FAA + (2ull + rb) * ND;
        float* out0 = (phase == 2) ? (ws + O_FAAN)      : (ws + O_FAA + (ull)wb * ND);
        float* out1 = (phase == 2) ? (ws + O_FAAN + ND) : (ws + O_FAA + (2ull + wb) * ND);
        softmin_faa_online(Crow, faa_r0, faa_r1, eps0, eps1, qs, out0, out1, i, phase, lane);
    } else {                              // g_bb
        const int q = w - 14336, div = q >> 10, i = q & 1023;
        const float eps = (phase == 2) ? 0.25f : ws[O_EPS + (ull)div * NIT + t];
        const unsigned short* Crow = uq + U_CYY + (ull)div * NS * NS + (ull)i * NS;
        const float* gbb_r = ws + O_GBB + ((ull)div * 2 + rb) * NS;
        float* outp = (phase == 2) ? (ws + O_GBBN + (ull)div * NS)
                                   : (ws + O_GBB + ((ull)div * 2 + wb) * NS);
        softmin_flat<2>(Crow, phase ? gbb_r : nullptr, B_LOG2, eps, qs, gbb_r, outp, i, phase, lane);
    }
}

// ---- dist[d] = mean(f_ab_n - f_aa_n) + mean(g_ab_n - g_bb_n) ----
__global__ __launch_bounds__(256)
void reduce_dist(float* __restrict__ ws)
{
    const int d = blockIdx.x;
    const int tix = threadIdx.x;
    float s = 0.0f;
    #pragma unroll
    for (int k = 0; k < 16; k++) {
        const int i = tix + k * 256;
        s += (ws[O_FABN + (ull)d * ND + i] - ws[O_FAAN + (ull)d * ND + i]) * (1.0f / 4096.0f);
    }
    #pragma unroll
    for (int k = 0; k < 4; k++) {
        const int j = tix + k * 256;
        s += (ws[O_GABN + (ull)d * NS + j] - ws[O_GBBN + (ull)d * NS + j]) * (1.0f / 1024.0f);
    }
    s = wave_sum(s);
    __shared__ float red[4];
    const int wid = tix >> 6, lane = tix & 63;
    if (lane == 0) red[wid] = s;
    __syncthreads();
    if (tix == 0) ws[O_DIST + d] = red[0] + red[1] + red[2] + red[3];
}

__global__ void finalize_k(const float* __restrict__ ws, float* __restrict__ out)
{
    const float x = ws[O_DIST + 1] - ws[O_DIST + 0];   // dist2 - dist1
    out[0] = 1.0f / (1.0f + expf(-x));
}

extern "C" void kernel_launch(void* const* d_in, const int* in_sizes, int n_in,
                              void* d_out, int out_size, void* d_ws, size_t ws_size,
                              hipStream_t stream)
{
    if (ws_size < WS_FLOATS * sizeof(float)) return;   // ~85 MB required

    const float* dmat = (const float*)d_in[0];
    const float* s1   = (const float*)d_in[1];
    const float* s2   = (const float*)d_in[2];
    const float* M    = (const float*)d_in[3];
    float* ws  = (float*)d_ws;
    float* out = (float*)d_out;
    unsigned short* uq = (unsigned short*)d_ws;

    float* Mt = ws + O_MT;
    float* xd = ws + O_XD;
    float* x1 = ws + O_X1;
    float* x2 = ws + O_X2;

    transpose_M_k<<<768, 256, 0, stream>>>(M, Mt);
    gemm_proj<<<dim3(4, 64), 256, 0, stream>>>(dmat, Mt, xd, 4096, 256, 768);
    gemm_proj<<<dim3(4, 16), 256, 0, stream>>>(s1,   Mt, x1, 1024, 256, 768);
    gemm_proj<<<dim3(4, 16), 256, 0, stream>>>(s2,   Mt, x2, 1024, 256, 768);
    row_norm<<<4096, 256, 0, stream>>>(xd, ws + O_ND_);
    row_norm<<<1024, 256, 0, stream>>>(x1, ws + O_N1);
    row_norm<<<1024, 256, 0, stream>>>(x2, ws + O_N2);
    colminmax_k<<<96, 256, 0, stream>>>(xd, x1, x2, ws);
    eps_k<<<1, 256, 0, stream>>>(ws);
    // pack bf16 hi/mid fragment buffers
    pack_bf16_k<<<256, 256, 0, stream>>>(xd, uq + P_XDH, uq + P_XDM);
    pack_bf16_k<<<64,  256, 0, stream>>>(x1, uq + P_X1H, uq + P_X1M);
    pack_bf16_k<<<64,  256, 0, stream>>>(x2, uq + P_X2H, uq + P_X2M);
    // cost matrices via MFMA (bf16x3); CT computed as swapped-operand GEMMs
    const float* qsp = ws + O_QS;
    const float* nd_ = ws + O_ND_;
    const float* n1  = ws + O_N1;
    const float* n2  = ws + O_N2;
    gemm_cost_mfma<<<dim3(64, 64), 256, 0, stream>>>(uq+P_XDH, uq+P_XDM, uq+P_XDH, uq+P_XDM, uq + U_CXX,           nd_, nd_, qsp, 4096);
    gemm_cost_mfma<<<dim3(16, 64), 256, 0, stream>>>(uq+P_XDH, uq+P_XDM, uq+P_X1H, uq+P_X1M, uq + U_CXY,           nd_, n1,  qsp, 1024);
    gemm_cost_mfma<<<dim3(64, 16), 256, 0, stream>>>(uq+P_X1H, uq+P_X1M, uq+P_XDH, uq+P_XDM, uq + U_CYX,           n1,  nd_, qsp, 4096);
    gemm_cost_mfma<<<dim3(16, 64), 256, 0, stream>>>(uq+P_XDH, uq+P_XDM, uq+P_X2H, uq+P_X2M, uq + U_CXY + ND*NS,   nd_, n2,  qsp, 1024);
    gemm_cost_mfma<<<dim3(64, 16), 256, 0, stream>>>(uq+P_X2H, uq+P_X2M, uq+P_XDH, uq+P_XDM, uq + U_CYX + ND*NS,   n2,  nd_, qsp, 4096);
    gemm_cost_mfma<<<dim3(16, 16), 256, 0, stream>>>(uq+P_X1H, uq+P_X1M, uq+P_X1H, uq+P_X1M, uq + U_CYY,           n1,  n1,  qsp, 1024);
    gemm_cost_mfma<<<dim3(16, 16), 256, 0, stream>>>(uq+P_X2H, uq+P_X2M, uq+P_X2H, uq+P_X2M, uq + U_CYY + NS*NS,   n2,  n2,  qsp, 1024);
    // Sinkhorn loop: 16384 waves, low-VGPR softmins, multi-launch barriers
    sinkhorn_phase<<<4096, 256, 0, stream>>>(ws, 0, 0);
    for (int t = 0; t < NIT; t++)
        sinkhorn_phase<<<4096, 256, 0, stream>>>(ws, 1, t);
    sinkhorn_phase<<<4096, 256, 0, stream>>>(ws, 2, 36);
    reduce_dist<<<2, 256, 0, stream>>>(ws);
    finalize_k<<<1, 1, 0, stream>>>(ws, out);
}

// Round 10
// 1681.991 us; speedup vs baseline: 1.3670x; 1.3670x over previous
//
#include <hip/hip_runtime.h>
#include <hip/hip_bf16.h>
#include <math.h>

using ull = unsigned long long;
typedef unsigned short u16x8 __attribute__((ext_vector_type(8)));
typedef __attribute__((ext_vector_type(8))) short bf16x8;   // 8 bf16 (4 VGPRs)
typedef __attribute__((ext_vector_type(4))) float f32x4;

// Problem constants
#define ND 4096ull   // n (xd rows)
#define NS 1024ull   // m (s1/s2 rows)
#define DOUT 256ull
#define DIN 768ull
#define NIT 36

// ---- u16 regions (ushort offsets into ws) ----
constexpr ull U_CXX = 0;                 // [ND*ND], shared by both divergences
constexpr ull U_CXY = U_CXX + ND*ND;     // [2][ND*NS]
constexpr ull U_CYX = U_CXY + 2*ND*NS;   // [2][NS*ND] transposed copies
constexpr ull U_CYY = U_CYX + 2*ND*NS;   // [2][NS*NS]
constexpr ull U_TOT = U_CYY + 2*NS*NS;   // ~71.3 MB
// bf16 hi/mid packed fragment buffers (ushort offsets)
constexpr ull P_XDH = U_TOT;
constexpr ull P_XDM = P_XDH + ND*DOUT;
constexpr ull P_X1H = P_XDM + ND*DOUT;
constexpr ull P_X1M = P_X1H + NS*DOUT;
constexpr ull P_X2H = P_X1M + NS*DOUT;
constexpr ull P_X2M = P_X2H + NS*DOUT;
constexpr ull U_END = P_X2M + NS*DOUT;   // even

// ---- fp32 region (float offsets into ws) ----
constexpr ull O_XD   = U_END / 2;
constexpr ull O_X1   = O_XD + ND*DOUT;
constexpr ull O_X2   = O_X1 + NS*DOUT;
constexpr ull O_MT   = O_X2 + NS*DOUT;       // [DOUT*DIN], dead after proj GEMMs
constexpr ull O_ND_  = O_MT + DOUT*DIN;
constexpr ull O_N1   = O_ND_ + ND;
constexpr ull O_N2   = O_N1 + NS;
constexpr ull O_FAB  = O_N2 + NS;            // [2 div][2 buf][ND]
constexpr ull O_GAB  = O_FAB + 4*ND;         // [2][2][NS]
constexpr ull O_FAA  = O_GAB + 4*NS;         // [2][2][ND]
constexpr ull O_GBB  = O_FAA + 4*ND;         // [2][2][NS]
constexpr ull O_FABN = O_GBB + 4*NS;         // [2][ND]
constexpr ull O_GABN = O_FABN + 2*ND;        // [2][NS]
constexpr ull O_FAAN = O_GABN + 2*NS;        // [2][ND]
constexpr ull O_GBBN = O_FAAN + 2*ND;        // [2][NS]
constexpr ull O_EPS  = O_GBBN + 2*NS;        // [2][NIT]
constexpr ull O_QS   = O_EPS + 2*NIT;        // [0]=quant scale, [1]=dequant
constexpr ull O_DIST = O_QS + 2;             // [2]
constexpr ull WS_FLOATS = O_DIST + 2;        // ~85 MB total
// diameter partials reuse dead Mt region
constexpr ull O_PMIN = O_MT;                 // [96*256]
constexpr ull O_PMAX = O_MT + 96*256;        // [96*256]

constexpr float LOG2E = 1.4426950408889634f;
constexpr float LN2   = 0.69314718055994531f;
constexpr float A_LOG2 = -12.0f;   // -log2(4096)
constexpr float B_LOG2 = -10.0f;   // -log2(1024)

__device__ __forceinline__ float wave_max(float v) {
    #pragma unroll
    for (int o = 32; o; o >>= 1) v = fmaxf(v, __shfl_xor(v, o));
    return v;
}
__device__ __forceinline__ float wave_sum(float v) {
    #pragma unroll
    for (int o = 32; o; o >>= 1) v += __shfl_xor(v, o);
    return v;
}

__device__ __forceinline__ unsigned short f2bf_rn(float x) {
    union { float f; unsigned u; } v; v.f = x;
    const unsigned r = v.u + 0x7FFFu + ((v.u >> 16) & 1u);
    return (unsigned short)(r >> 16);
}
__device__ __forceinline__ float bf2f(unsigned short b) {
    union { unsigned u; float f; } v; v.u = ((unsigned)b) << 16; return v.f;
}

// ---- transpose M [DIN x DOUT] -> Mt [DOUT x DIN] ----
__global__ __launch_bounds__(256)
void transpose_M_k(const float* __restrict__ M, float* __restrict__ Mt)
{
    int idx = blockIdx.x * 256 + threadIdx.x;
    int r = idx >> 8;
    int c = idx & 255;
    Mt[(size_t)c * DIN + r] = M[idx];
}

// ---- projection GEMM: P = A[MxK] @ B[NxK]^T (64x64 tile, 4x4/thread) ----
__global__ __launch_bounds__(256)
void gemm_proj(const float* __restrict__ A, const float* __restrict__ B,
               float* __restrict__ C, int M, int N, int K)
{
    __shared__ __align__(16) float As[16][68];
    __shared__ __align__(16) float Bs[16][68];
    const int m0 = blockIdx.y * 64, n0 = blockIdx.x * 64;
    const int t = threadIdx.x;
    const int lk = t & 15, lr = t >> 4;
    const int tm = t >> 4, tn = t & 15;
    float acc[4][4] = {};
    for (int k0 = 0; k0 < K; k0 += 16) {
        #pragma unroll
        for (int r = 0; r < 4; r++) {
            As[lk][lr + r*16] = A[(size_t)(m0 + lr + r*16) * K + (k0 + lk)];
            Bs[lk][lr + r*16] = B[(size_t)(n0 + lr + r*16) * K + (k0 + lk)];
        }
        __syncthreads();
        #pragma unroll
        for (int k = 0; k < 16; k++) {
            const float4 a4 = *(const float4*)&As[k][tm*4];
            const float4 b4 = *(const float4*)&Bs[k][tn*4];
            const float av[4] = {a4.x, a4.y, a4.z, a4.w};
            const float bv[4] = {b4.x, b4.y, b4.z, b4.w};
            #pragma unroll
            for (int i = 0; i < 4; i++)
                #pragma unroll
                for (int j = 0; j < 4; j++)
                    acc[i][j] = fmaf(av[i], bv[j], acc[i][j]);
        }
        __syncthreads();
    }
    #pragma unroll
    for (int i = 0; i < 4; i++)
        #pragma unroll
        for (int j = 0; j < 4; j++)
            C[(size_t)(m0 + tm*4 + i) * N + (n0 + tn*4 + j)] = acc[i][j];
}

// ---- pack fp32 [R][256] -> bf16 hi/mid in MFMA fragment order ----
// slot(p,kb,l,e) = ((p*8+kb)*64+l)*8+e  holds  X[p*16+(l&15)][kb*32+(l>>4)*8+e]
__global__ __launch_bounds__(256)
void pack_bf16_k(const float* __restrict__ X,
                 unsigned short* __restrict__ Phi, unsigned short* __restrict__ Pmi)
{
    const int p = blockIdx.x;
    const int t = threadIdx.x;
    #pragma unroll
    for (int s = t; s < 512; s += 256) {
        const int kb = s >> 6, l = s & 63;
        const int row = p * 16 + (l & 15);
        const int k0 = kb * 32 + ((l >> 4) << 3);
        const float* src = X + (ull)row * DOUT + k0;
        u16x8 hi, mi;
        #pragma unroll
        for (int e = 0; e < 8; e++) {
            const float x = src[e];
            const unsigned short h = f2bf_rn(x);
            hi[e] = h;
            mi[e] = f2bf_rn(x - bf2f(h));
        }
        const ull o = (((ull)p * 8 + kb) * 64 + l) * 8;
        *(u16x8*)&Phi[o] = hi;
        *(u16x8*)&Pmi[o] = mi;
    }
}

// ---- MFMA cost GEMM (bf16x3 split), 128x64 block tile, 2 A-panels/wave ----
__device__ __forceinline__ unsigned int quant16(float c, float s) {
    return __float2uint_rn(fminf(c * s, 65535.0f));
}

__global__ __launch_bounds__(256)
void gemm_cost_mfma(const unsigned short* __restrict__ Ahi, const unsigned short* __restrict__ Ami,
                    const unsigned short* __restrict__ Bhi, const unsigned short* __restrict__ Bmi,
                    unsigned short* __restrict__ C,
                    const float* __restrict__ na, const float* __restrict__ nb,
                    const float* __restrict__ qsp, int N)
{
    const int l = threadIdx.x & 63;
    const int w = threadIdx.x >> 6;
    const int n0 = blockIdx.x * 64, m0 = blockIdx.y * 128;
    const int pA0 = (m0 >> 4) + w * 2;   // 2 A panels per wave (32 rows)
    const int pB0 = n0 >> 4;
    f32x4 acc[2][4] = {};
    #pragma unroll
    for (int kb = 0; kb < 8; kb++) {
        const ull a0o = (((ull)(pA0 + 0) * 8 + kb) * 64 + l) * 8;
        const ull a1o = (((ull)(pA0 + 1) * 8 + kb) * 64 + l) * 8;
        const bf16x8 aH0 = *(const bf16x8*)&Ahi[a0o];
        const bf16x8 aM0 = *(const bf16x8*)&Ami[a0o];
        const bf16x8 aH1 = *(const bf16x8*)&Ahi[a1o];
        const bf16x8 aM1 = *(const bf16x8*)&Ami[a1o];
        #pragma unroll
        for (int j = 0; j < 4; j++) {
            const ull bo = (((ull)(pB0 + j) * 8 + kb) * 64 + l) * 8;
            const bf16x8 bH = *(const bf16x8*)&Bhi[bo];
            const bf16x8 bM = *(const bf16x8*)&Bmi[bo];
            acc[0][j] = __builtin_amdgcn_mfma_f32_16x16x32_bf16(aH0, bH, acc[0][j], 0, 0, 0);
            acc[0][j] = __builtin_amdgcn_mfma_f32_16x16x32_bf16(aH0, bM, acc[0][j], 0, 0, 0);
            acc[0][j] = __builtin_amdgcn_mfma_f32_16x16x32_bf16(aM0, bH, acc[0][j], 0, 0, 0);
            acc[1][j] = __builtin_amdgcn_mfma_f32_16x16x32_bf16(aH1, bH, acc[1][j], 0, 0, 0);
            acc[1][j] = __builtin_amdgcn_mfma_f32_16x16x32_bf16(aH1, bM, acc[1][j], 0, 0, 0);
            acc[1][j] = __builtin_amdgcn_mfma_f32_16x16x32_bf16(aM1, bH, acc[1][j], 0, 0, 0);
        }
    }
    // C/D layout (m89-verified): col = lane&15, row = (lane>>4)*4 + reg
    const float s = qsp[0];
    const int col = l & 15;
    float nbj[4];
    #pragma unroll
    for (int j = 0; j < 4; j++) nbj[j] = nb[n0 + j * 16 + col];
    #pragma unroll
    for (int i = 0; i < 2; i++) {
        const int row0 = m0 + w * 32 + i * 16 + ((l >> 4) << 2);
        #pragma unroll
        for (int r = 0; r < 4; r++) {
            const float nar = na[row0 + r];
            const ull rowb = (ull)(row0 + r) * N + n0;
            #pragma unroll
            for (int j = 0; j < 4; j++)
                C[rowb + j * 16 + col] =
                    (unsigned short)quant16(0.5f * fmaxf(nar + nbj[j] - 2.0f * acc[i][j][r], 0.0f), s);
        }
    }
}

// ---- row squared-norms ----
__global__ __launch_bounds__(256)
void row_norm(const float* __restrict__ x, float* __restrict__ o)
{
    const int i = blockIdx.x;
    const float v = x[(size_t)i * DOUT + threadIdx.x];
    float s = wave_sum(v * v);
    __shared__ float red[4];
    const int wid = threadIdx.x >> 6, lane = threadIdx.x & 63;
    if (lane == 0) red[wid] = s;
    __syncthreads();
    if (threadIdx.x == 0) o[i] = red[0] + red[1] + red[2] + red[3];
}

// ---- per-column min/max partials ----
__global__ __launch_bounds__(256)
void colminmax_k(const float* __restrict__ xd, const float* __restrict__ x1,
                 const float* __restrict__ x2, float* __restrict__ ws)
{
    const int b = blockIdx.x, c = threadIdx.x;
    const float* src; int r0;
    if (b < 64)      { src = xd; r0 = b * 64; }
    else if (b < 80) { src = x1; r0 = (b - 64) * 64; }
    else             { src = x2; r0 = (b - 80) * 64; }
    float mn = 3.4e38f, mx = -3.4e38f;
    for (int r = 0; r < 64; r++) {
        const float v = src[(size_t)(r0 + r) * DOUT + c];
        mn = fminf(mn, v); mx = fmaxf(mx, v);
    }
    ws[O_PMIN + (ull)b * 256 + c] = mn;
    ws[O_PMAX + (ull)b * 256 + c] = mx;
}

// ---- partials -> diam -> eps schedule + quant scale ----
__global__ __launch_bounds__(256)
void eps_k(float* __restrict__ ws)
{
    const int c = threadIdx.x;
    const float* pmin = ws + O_PMIN;
    const float* pmax = ws + O_PMAX;
    float mnd = 3.4e38f, mxd = -3.4e38f;
    float mn1 = 3.4e38f, mx1 = -3.4e38f;
    float mn2 = 3.4e38f, mx2 = -3.4e38f;
    for (int b = 0;  b < 64; b++) { mnd = fminf(mnd, pmin[b*256+c]); mxd = fmaxf(mxd, pmax[b*256+c]); }
    for (int b = 64; b < 80; b++) { mn1 = fminf(mn1, pmin[b*256+c]); mx1 = fmaxf(mx1, pmax[b*256+c]); }
    for (int b = 80; b < 96; b++) { mn2 = fminf(mn2, pmin[b*256+c]); mx2 = fmaxf(mx2, pmax[b*256+c]); }
    const float d1 = fmaxf(mxd, mx1) - fminf(mnd, mn1);
    const float d2 = fmaxf(mxd, mx2) - fminf(mnd, mn2);
    float s1 = wave_sum(d1 * d1);
    float s2 = wave_sum(d2 * d2);
    __shared__ float r1[4], r2[4];
    const int wid = c >> 6, lane = c & 63;
    if (lane == 0) { r1[wid] = s1; r2[wid] = s2; }
    __syncthreads();
    if (c == 0) {
        const float d1s = r1[0]+r1[1]+r1[2]+r1[3];
        const float d2s = r2[0]+r2[1]+r2[2]+r2[3];
        const float cb = 0.5f * fmaxf(d1s, d2s) * 1.02f + 1.0f;
        ws[O_QS]     = 65535.0f / cb;
        ws[O_QS + 1] = cb / 65535.0f;
    }
    if (c < 2 * NIT) {
        const int div = c / NIT, tt = c % NIT;
        const float ss = div ? (r2[0]+r2[1]+r2[2]+r2[3]) : (r1[0]+r1[1]+r1[2]+r1[3]);
        const float diam = sqrtf(ss) + 1e-6f;
        const float sc = fmaxf(0.5f, diam * powf(0.8f, (float)tt));
        ws[O_EPS + (ull)div * NIT + tt] = sc * sc;
    }
}

__device__ __forceinline__ float tmax8(const float* v) {
    return fmaxf(fmaxf(fmaxf(v[0],v[1]),fmaxf(v[2],v[3])),
                 fmaxf(fmaxf(v[4],v[5]),fmaxf(v[6],v[7])));
}

// ---- flat softmin for short rows (NC chunks of 512; v kept in regs) ----
template<int NC>
__device__ __forceinline__ void softmin_flat(
    const unsigned short* __restrict__ Crow, const float* __restrict__ hvec,
    float hc2, float eps, float qs,
    const float* __restrict__ selfv, float* __restrict__ outp,
    int row, int phase, int lane)
{
    const float ie2 = LOG2E / eps;
    const float qsc = -qs * ie2;
    float v[NC * 8];
    #pragma unroll
    for (int c = 0; c < NC; c++) {
        const int off = c * 512 + lane * 8;
        const u16x8 q = *(const u16x8*)&Crow[off];
        if (hvec) {
            const float4 ha = *(const float4*)&hvec[off];
            const float4 hb = *(const float4*)&hvec[off + 4];
            const float hv[8] = {ha.x, ha.y, ha.z, ha.w, hb.x, hb.y, hb.z, hb.w};
            #pragma unroll
            for (int e = 0; e < 8; e++)
                v[c*8 + e] = fmaf((float)q[e], qsc, fmaf(hv[e], ie2, hc2));
        } else {
            #pragma unroll
            for (int e = 0; e < 8; e++)
                v[c*8 + e] = fmaf((float)q[e], qsc, hc2);
        }
    }
    float m = v[0];
    #pragma unroll
    for (int k = 1; k < NC * 8; k++) m = fmaxf(m, v[k]);
    m = wave_max(m);
    float sa[4] = {0.0f, 0.0f, 0.0f, 0.0f};
    #pragma unroll
    for (int k = 0; k < NC * 8; k++) sa[k & 3] += exp2f(v[k] - m);
    float s = wave_sum((sa[0] + sa[1]) + (sa[2] + sa[3]));
    if (lane == 0) {
        float res = -eps * LN2 * (m + log2f(s));
        if (phase == 1) res = 0.5f * (selfv[row] + res);
        outp[row] = res;
    }
}

// ---- online softmin for long rows (8 live values; low VGPR) ----
template<int NC>
__device__ __forceinline__ void softmin_online(
    const unsigned short* __restrict__ Crow, const float* __restrict__ hvec,
    float hc2, float eps, float qs,
    const float* __restrict__ selfv, float* __restrict__ outp,
    int row, int phase, int lane)
{
    const float ie2 = LOG2E / eps;
    const float qsc = -qs * ie2;
    float m = -1e30f, s = 0.0f;
    #pragma unroll
    for (int c = 0; c < NC; c++) {
        const int off = c * 512 + lane * 8;
        const u16x8 q = *(const u16x8*)&Crow[off];
        float v[8];
        if (hvec) {
            const float4 ha = *(const float4*)&hvec[off];
            const float4 hb = *(const float4*)&hvec[off + 4];
            v[0] = fmaf((float)q[0], qsc, fmaf(ha.x, ie2, hc2));
            v[1] = fmaf((float)q[1], qsc, fmaf(ha.y, ie2, hc2));
            v[2] = fmaf((float)q[2], qsc, fmaf(ha.z, ie2, hc2));
            v[3] = fmaf((float)q[3], qsc, fmaf(ha.w, ie2, hc2));
            v[4] = fmaf((float)q[4], qsc, fmaf(hb.x, ie2, hc2));
            v[5] = fmaf((float)q[5], qsc, fmaf(hb.y, ie2, hc2));
            v[6] = fmaf((float)q[6], qsc, fmaf(hb.z, ie2, hc2));
            v[7] = fmaf((float)q[7], qsc, fmaf(hb.w, ie2, hc2));
        } else {
            #pragma unroll
            for (int e = 0; e < 8; e++) v[e] = fmaf((float)q[e], qsc, hc2);
        }
        const float cm = tmax8(v);
        const float mn = fmaxf(m, cm);
        float p0 = exp2f(v[0]-mn) + exp2f(v[1]-mn);
        float p1 = exp2f(v[2]-mn) + exp2f(v[3]-mn);
        float p2 = exp2f(v[4]-mn) + exp2f(v[5]-mn);
        float p3 = exp2f(v[6]-mn) + exp2f(v[7]-mn);
        s = fmaf(s, exp2f(m - mn), (p0 + p1) + (p2 + p3));
        m = mn;
    }
    const float mt = wave_max(m);
    const float st = wave_sum(s * exp2f(m - mt));
    if (lane == 0) {
        float res = -eps * LN2 * (mt + log2f(st));
        if (phase == 1) res = 0.5f * (selfv[row] + res);
        outp[row] = res;
    }
}

// ---- faa: ONE online pass over a C_xx row, BOTH divergences (cvt once) ----
__device__ __forceinline__ void softmin_faa_online(
    const unsigned short* __restrict__ Crow,
    const float* __restrict__ h0, const float* __restrict__ h1,
    float eps0, float eps1, float qs,
    float* __restrict__ out0, float* __restrict__ out1,
    int row, int phase, int lane)
{
    const float ie0 = LOG2E / eps0, ie1 = LOG2E / eps1;
    const float qs0 = -qs * ie0, qs1 = -qs * ie1;
    float m0 = -1e30f, s0 = 0.0f, m1 = -1e30f, s1 = 0.0f;
    #pragma unroll
    for (int c = 0; c < 8; c++) {
        const int off = c * 512 + lane * 8;
        const u16x8 q = *(const u16x8*)&Crow[off];
        float cq[8];
        #pragma unroll
        for (int e = 0; e < 8; e++) cq[e] = (float)q[e];
        float v[8];
        // divergence 0
        if (phase) {
            const float4 a = *(const float4*)&h0[off];
            const float4 b = *(const float4*)&h0[off + 4];
            v[0] = fmaf(cq[0], qs0, fmaf(a.x, ie0, A_LOG2));
            v[1] = fmaf(cq[1], qs0, fmaf(a.y, ie0, A_LOG2));
            v[2] = fmaf(cq[2], qs0, fmaf(a.z, ie0, A_LOG2));
            v[3] = fmaf(cq[3], qs0, fmaf(a.w, ie0, A_LOG2));
            v[4] = fmaf(cq[4], qs0, fmaf(b.x, ie0, A_LOG2));
            v[5] = fmaf(cq[5], qs0, fmaf(b.y, ie0, A_LOG2));
            v[6] = fmaf(cq[6], qs0, fmaf(b.z, ie0, A_LOG2));
            v[7] = fmaf(cq[7], qs0, fmaf(b.w, ie0, A_LOG2));
        } else {
            #pragma unroll
            for (int e = 0; e < 8; e++) v[e] = fmaf(cq[e], qs0, A_LOG2);
        }
        {
            const float mn = fmaxf(m0, tmax8(v));
            float p0 = exp2f(v[0]-mn) + exp2f(v[1]-mn);
            float p1 = exp2f(v[2]-mn) + exp2f(v[3]-mn);
            float p2 = exp2f(v[4]-mn) + exp2f(v[5]-mn);
            float p3 = exp2f(v[6]-mn) + exp2f(v[7]-mn);
            s0 = fmaf(s0, exp2f(m0 - mn), (p0 + p1) + (p2 + p3));
            m0 = mn;
        }
        // divergence 1
        if (phase) {
            const float4 a = *(const float4*)&h1[off];
            const float4 b = *(const float4*)&h1[off + 4];
            v[0] = fmaf(cq[0], qs1, fmaf(a.x, ie1, A_LOG2));
            v[1] = fmaf(cq[1], qs1, fmaf(a.y, ie1, A_LOG2));
            v[2] = fmaf(cq[2], qs1, fmaf(a.z, ie1, A_LOG2));
            v[3] = fmaf(cq[3], qs1, fmaf(a.w, ie1, A_LOG2));
            v[4] = fmaf(cq[4], qs1, fmaf(b.x, ie1, A_LOG2));
            v[5] = fmaf(cq[5], qs1, fmaf(b.y, ie1, A_LOG2));
            v[6] = fmaf(cq[6], qs1, fmaf(b.z, ie1, A_LOG2));
            v[7] = fmaf(cq[7], qs1, fmaf(b.w, ie1, A_LOG2));
        } else {
            #pragma unroll
            for (int e = 0; e < 8; e++) v[e] = fmaf(cq[e], qs1, A_LOG2);
        }
        {
            const float mn = fmaxf(m1, tmax8(v));
            float p0 = exp2f(v[0]-mn) + exp2f(v[1]-mn);
            float p1 = exp2f(v[2]-mn) + exp2f(v[3]-mn);
            float p2 = exp2f(v[4]-mn) + exp2f(v[5]-mn);
            float p3 = exp2f(v[6]-mn) + exp2f(v[7]-mn);
            s1 = fmaf(s1, exp2f(m1 - mn), (p0 + p1) + (p2 + p3));
            m1 = mn;
        }
    }
    float mt = wave_max(m0);
    float st = wave_sum(s0 * exp2f(m0 - mt));
    if (lane == 0) {
        float res = -eps0 * LN2 * (mt + log2f(st));
        if (phase == 1) res = 0.5f * (h0[row] + res);   // h0 == faa_r0 (self)
        out0[row] = res;
    }
    mt = wave_max(m1);
    st = wave_sum(s1 * exp2f(m1 - mt));
    if (lane == 0) {
        float res = -eps1 * LN2 * (mt + log2f(st));
        if (phase == 1) res = 0.5f * (h1[row] + res);
        out1[row] = res;
    }
}

// ---- fused Sinkhorn step: 16384 waves (4096 blocks), low-VGPR softmins ----
// NO forced min-waves bound (r9's (256,8) capped VGPR at 32 -> scratch spills)
//  [0,8192)      ft   (C_xy rows, len 1024), div = w>>12
//  [8192,10240)  gt   (C_yx rows, len 4096), div = (w-8192)>>10
//  [10240,14336) f_aa (C_xx rows), both divergences in ONE row pass
//  [14336,16384) g_bb (C_yy rows, len 1024), div = (w-14336)>>10
__global__ __launch_bounds__(256)
void sinkhorn_phase(float* __restrict__ ws, int phase, int t)
{
    const unsigned short* uq = (const unsigned short*)ws;
    const int wid = threadIdx.x >> 6, lane = threadIdx.x & 63;
    const int w = blockIdx.x * 4 + wid;
    const float qs = ws[O_QS + 1];
    int rb, wb;
    if (phase == 0) { rb = 0; wb = 0; }
    else { rb = t & 1; wb = rb ^ 1; }   // phase 2 passes t=36 -> rb=0

    if (w < 8192) {                       // ft -> f_ab
        const int div = w >> 12, i = w & 4095;
        const float eps = (phase == 2) ? 0.25f : ws[O_EPS + (ull)div * NIT + t];
        const unsigned short* Crow = uq + U_CXY + (ull)div * ND * NS + (ull)i * NS;
        const float* gab_r = ws + O_GAB + ((ull)div * 2 + rb) * NS;
        const float* fab_r = ws + O_FAB + ((ull)div * 2 + rb) * ND;
        float* outp = (phase == 2) ? (ws + O_FABN + (ull)div * ND)
                                   : (ws + O_FAB + ((ull)div * 2 + wb) * ND);
        softmin_flat<2>(Crow, phase ? gab_r : nullptr, B_LOG2, eps, qs, fab_r, outp, i, phase, lane);
    } else if (w < 10240) {               // gt -> g_ab
        const int q = w - 8192, div = q >> 10, j = q & 1023;
        const float eps = (phase == 2) ? 0.25f : ws[O_EPS + (ull)div * NIT + t];
        const unsigned short* Crow = uq + U_CYX + (ull)div * ND * NS + (ull)j * ND;
        const float* fab_r = ws + O_FAB + ((ull)div * 2 + rb) * ND;
        const float* gab_r = ws + O_GAB + ((ull)div * 2 + rb) * NS;
        float* outp = (phase == 2) ? (ws + O_GABN + (ull)div * NS)
                                   : (ws + O_GAB + ((ull)div * 2 + wb) * NS);
        softmin_online<8>(Crow, phase ? fab_r : nullptr, A_LOG2, eps, qs, gab_r, outp, j, phase, lane);
    } else if (w < 14336) {               // f_aa, both divergences, one pass
        const int i = w - 10240;
        const float eps0 = (phase == 2) ? 0.25f : ws[O_EPS + t];
        const float eps1 = (phase == 2) ? 0.25f : ws[O_EPS + NIT + t];
        const unsigned short* Crow = uq + U_CXX + (ull)i * ND;
        const float* faa_r0 = ws + O_FAA + (ull)rb * ND;
        const float* faa_r1 = ws + O_FAA + (2ull + rb) * ND;
        float* out0 = (phase == 2) ? (ws + O_FAAN)      : (ws + O_FAA + (ull)wb * ND);
        float* out1 = (phase == 2) ? (ws + O_FAAN + ND) : (ws + O_FAA + (2ull + wb) * ND);
        softmin_faa_online(Crow, faa_r0, faa_r1, eps0, eps1, qs, out0, out1, i, phase, lane);
    } else {                              // g_bb
        const int q = w - 14336, div = q >> 10, i = q & 1023;
        const float eps = (phase == 2) ? 0.25f : ws[O_EPS + (ull)div * NIT + t];
        const unsigned short* Crow = uq + U_CYY + (ull)div * NS * NS + (ull)i * NS;
        const float* gbb_r = ws + O_GBB + ((ull)div * 2 + rb) * NS;
        float* outp = (phase == 2) ? (ws + O_GBBN + (ull)div * NS)
                                   : (ws + O_GBB + ((ull)div * 2 + wb) * NS);
        softmin_flat<2>(Crow, phase ? gbb_r : nullptr, B_LOG2, eps, qs, gbb_r, outp, i, phase, lane);
    }
}

// ---- dist[d] = mean(f_ab_n - f_aa_n) + mean(g_ab_n - g_bb_n) ----
__global__ __launch_bounds__(256)
void reduce_dist(float* __restrict__ ws)
{
    const int d = blockIdx.x;
    const int tix = threadIdx.x;
    float s = 0.0f;
    #pragma unroll
    for (int k = 0; k < 16; k++) {
        const int i = tix + k * 256;
        s += (ws[O_FABN + (ull)d * ND + i] - ws[O_FAAN + (ull)d * ND + i]) * (1.0f / 4096.0f);
    }
    #pragma unroll
    for (int k = 0; k < 4; k++) {
        const int j = tix + k * 256;
        s += (ws[O_GABN + (ull)d * NS + j] - ws[O_GBBN + (ull)d * NS + j]) * (1.0f / 1024.0f);
    }
    s = wave_sum(s);
    __shared__ float red[4];
    const int wid = tix >> 6, lane = tix & 63;
    if (lane == 0) red[wid] = s;
    __syncthreads();
    if (tix == 0) ws[O_DIST + d] = red[0] + red[1] + red[2] + red[3];
}

__global__ void finalize_k(const float* __restrict__ ws, float* __restrict__ out)
{
    const float x = ws[O_DIST + 1] - ws[O_DIST + 0];   // dist2 - dist1
    out[0] = 1.0f / (1.0f + expf(-x));
}

extern "C" void kernel_launch(void* const* d_in, const int* in_sizes, int n_in,
                              void* d_out, int out_size, void* d_ws, size_t ws_size,
                              hipStream_t stream)
{
    if (ws_size < WS_FLOATS * sizeof(float)) return;   // ~85 MB required

    const float* dmat = (const float*)d_in[0];
    const float* s1   = (const float*)d_in[1];
    const float* s2   = (const float*)d_in[2];
    const float* M    = (const float*)d_in[3];
    float* ws  = (float*)d_ws;
    float* out = (float*)d_out;
    unsigned short* uq = (unsigned short*)d_ws;

    float* Mt = ws + O_MT;
    float* xd = ws + O_XD;
    float* x1 = ws + O_X1;
    float* x2 = ws + O_X2;

    transpose_M_k<<<768, 256, 0, stream>>>(M, Mt);
    gemm_proj<<<dim3(4, 64), 256, 0, stream>>>(dmat, Mt, xd, 4096, 256, 768);
    gemm_proj<<<dim3(4, 16), 256, 0, stream>>>(s1,   Mt, x1, 1024, 256, 768);
    gemm_proj<<<dim3(4, 16), 256, 0, stream>>>(s2,   Mt, x2, 1024, 256, 768);
    row_norm<<<4096, 256, 0, stream>>>(xd, ws + O_ND_);
    row_norm<<<1024, 256, 0, stream>>>(x1, ws + O_N1);
    row_norm<<<1024, 256, 0, stream>>>(x2, ws + O_N2);
    colminmax_k<<<96, 256, 0, stream>>>(xd, x1, x2, ws);
    eps_k<<<1, 256, 0, stream>>>(ws);
    // pack bf16 hi/mid fragment buffers
    pack_bf16_k<<<256, 256, 0, stream>>>(xd, uq + P_XDH, uq + P_XDM);
    pack_bf16_k<<<64,  256, 0, stream>>>(x1, uq + P_X1H, uq + P_X1M);
    pack_bf16_k<<<64,  256, 0, stream>>>(x2, uq + P_X2H, uq + P_X2M);
    // cost matrices via MFMA (bf16x3, 128x64 tile); CT as swapped-operand GEMMs
    const float* qsp = ws + O_QS;
    const float* nd_ = ws + O_ND_;
    const float* n1  = ws + O_N1;
    const float* n2  = ws + O_N2;
    gemm_cost_mfma<<<dim3(64, 32), 256, 0, stream>>>(uq+P_XDH, uq+P_XDM, uq+P_XDH, uq+P_XDM, uq + U_CXX,         nd_, nd_, qsp, 4096);
    gemm_cost_mfma<<<dim3(16, 32), 256, 0, stream>>>(uq+P_XDH, uq+P_XDM, uq+P_X1H, uq+P_X1M, uq + U_CXY,         nd_, n1,  qsp, 1024);
    gemm_cost_mfma<<<dim3(64, 8),  256, 0, stream>>>(uq+P_X1H, uq+P_X1M, uq+P_XDH, uq+P_XDM, uq + U_CYX,         n1,  nd_, qsp, 4096);
    gemm_cost_mfma<<<dim3(16, 32), 256, 0, stream>>>(uq+P_XDH, uq+P_XDM, uq+P_X2H, uq+P_X2M, uq + U_CXY + ND*NS, nd_, n2,  qsp, 1024);
    gemm_cost_mfma<<<dim3(64, 8),  256, 0, stream>>>(uq+P_X2H, uq+P_X2M, uq+P_XDH, uq+P_XDM, uq + U_CYX + ND*NS, n2,  nd_, qsp, 4096);
    gemm_cost_mfma<<<dim3(16, 8),  256, 0, stream>>>(uq+P_X1H, uq+P_X1M, uq+P_X1H, uq+P_X1M, uq + U_CYY,         n1,  n1,  qsp, 1024);
    gemm_cost_mfma<<<dim3(16, 8),  256, 0, stream>>>(uq+P_X2H, uq+P_X2M, uq+P_X2H, uq+P_X2M, uq + U_CYY + NS*NS, n2,  n2,  qsp, 1024);
    // Sinkhorn loop: 16384 waves, low-VGPR softmins, multi-launch barriers
    sinkhorn_phase<<<4096, 256, 0, stream>>>(ws, 0, 0);
    for (int t = 0; t < NIT; t++)
        sinkhorn_phase<<<4096, 256, 0, stream>>>(ws, 1, t);
    sinkhorn_phase<<<4096, 256, 0, stream>>>(ws, 2, 36);
    reduce_dist<<<2, 256, 0, stream>>>(ws);
    finalize_k<<<1, 1, 0, stream>>>(ws, out);
}

// Round 11
// 1430.986 us; speedup vs baseline: 1.6068x; 1.1754x over previous
//
#include <hip/hip_runtime.h>
#include <hip/hip_bf16.h>
#include <math.h>

using ull = unsigned long long;
typedef unsigned short u16x8 __attribute__((ext_vector_type(8)));
typedef __attribute__((ext_vector_type(8))) short bf16x8;   // 8 bf16 (4 VGPRs)
typedef __attribute__((ext_vector_type(4))) float f32x4;

// Problem constants
#define ND 4096ull   // n (xd rows)
#define NS 1024ull   // m (s1/s2 rows)
#define DOUT 256ull
#define DIN 768ull
#define NIT 36

// ---- u16 regions (ushort offsets into ws) ----
constexpr ull U_CXX = 0;                 // [ND*ND], shared by both divergences
constexpr ull U_CXY = U_CXX + ND*ND;     // [2][ND*NS]
constexpr ull U_CYX = U_CXY + 2*ND*NS;   // [2][NS*ND] transposed copies
constexpr ull U_CYY = U_CYX + 2*ND*NS;   // [2][NS*NS]
constexpr ull U_TOT = U_CYY + 2*NS*NS;   // ~71.3 MB
// bf16 hi/mid packed fragment buffers for cost GEMMs (K=256)
constexpr ull P_XDH = U_TOT;
constexpr ull P_XDM = P_XDH + ND*DOUT;
constexpr ull P_X1H = P_XDM + ND*DOUT;
constexpr ull P_X1M = P_X1H + NS*DOUT;
constexpr ull P_X2H = P_X1M + NS*DOUT;
constexpr ull P_X2M = P_X2H + NS*DOUT;
// bf16 hi/mid packed fragment buffers for projection GEMMs (K=768)
constexpr ull P_DH  = P_X2M + NS*DOUT;
constexpr ull P_DM  = P_DH + ND*DIN;
constexpr ull P_S1H = P_DM + ND*DIN;
constexpr ull P_S1M = P_S1H + NS*DIN;
constexpr ull P_S2H = P_S1M + NS*DIN;
constexpr ull P_S2M = P_S2H + NS*DIN;
constexpr ull P_MTH = P_S2M + NS*DIN;
constexpr ull P_MTM = P_MTH + DOUT*DIN;
constexpr ull U_END = P_MTM + DOUT*DIN;  // even

// ---- fp32 region (float offsets into ws) ----
constexpr ull O_XD   = U_END / 2;
constexpr ull O_X1   = O_XD + ND*DOUT;
constexpr ull O_X2   = O_X1 + NS*DOUT;
constexpr ull O_MT   = O_X2 + NS*DOUT;       // [DOUT*DIN], dead after Mt pack
constexpr ull O_ND_  = O_MT + DOUT*DIN;
constexpr ull O_N1   = O_ND_ + ND;
constexpr ull O_N2   = O_N1 + NS;
constexpr ull O_FAB  = O_N2 + NS;            // [2 div][2 buf][ND]
constexpr ull O_GAB  = O_FAB + 4*ND;         // [2][2][NS]
constexpr ull O_FAA  = O_GAB + 4*NS;         // [2][2][ND]
constexpr ull O_GBB  = O_FAA + 4*ND;         // [2][2][NS]
constexpr ull O_FABN = O_GBB + 4*NS;         // [2][ND]
constexpr ull O_GABN = O_FABN + 2*ND;        // [2][NS]
constexpr ull O_FAAN = O_GABN + 2*NS;        // [2][ND]
constexpr ull O_GBBN = O_FAAN + 2*ND;        // [2][NS]
constexpr ull O_EPS  = O_GBBN + 2*NS;        // [2][NIT]
constexpr ull O_QS   = O_EPS + 2*NIT;        // [0]=quant scale, [1]=dequant
constexpr ull O_DIST = O_QS + 2;             // [2]
constexpr ull WS_FLOATS = O_DIST + 2;        // ~105 MB total
// diameter partials reuse dead Mt region (after Mt is packed)
constexpr ull O_PMIN = O_MT;                 // [96*256]
constexpr ull O_PMAX = O_MT + 96*256;        // [96*256]

constexpr float LOG2E = 1.4426950408889634f;
constexpr float LN2   = 0.69314718055994531f;
constexpr float A_LOG2 = -12.0f;   // -log2(4096)
constexpr float B_LOG2 = -10.0f;   // -log2(1024)

__device__ __forceinline__ float wave_max(float v) {
    #pragma unroll
    for (int o = 32; o; o >>= 1) v = fmaxf(v, __shfl_xor(v, o));
    return v;
}
__device__ __forceinline__ float wave_sum(float v) {
    #pragma unroll
    for (int o = 32; o; o >>= 1) v += __shfl_xor(v, o);
    return v;
}

__device__ __forceinline__ unsigned short f2bf_rn(float x) {
    union { float f; unsigned u; } v; v.f = x;
    const unsigned r = v.u + 0x7FFFu + ((v.u >> 16) & 1u);
    return (unsigned short)(r >> 16);
}
__device__ __forceinline__ float bf2f(unsigned short b) {
    union { unsigned u; float f; } v; v.u = ((unsigned)b) << 16; return v.f;
}

// ---- transpose M [DIN x DOUT] -> Mt [DOUT x DIN] ----
__global__ __launch_bounds__(256)
void transpose_M_k(const float* __restrict__ M, float* __restrict__ Mt)
{
    int idx = blockIdx.x * 256 + threadIdx.x;
    int r = idx >> 8;
    int c = idx & 255;
    Mt[(size_t)c * DIN + r] = M[idx];
}

// ---- pack fp32 [R][KB*32] -> bf16 hi/mid in MFMA fragment order ----
// slot(p,kb,l,e) = ((p*KB+kb)*64+l)*8+e  holds  X[p*16+(l&15)][kb*32+(l>>4)*8+e]
__global__ __launch_bounds__(256)
void pack_bf16_gen(const float* __restrict__ X,
                   unsigned short* __restrict__ Phi, unsigned short* __restrict__ Pmi,
                   int KB)
{
    const int p = blockIdx.x;
    const int t = threadIdx.x;
    const int K = KB * 32;
    for (int s = t; s < KB * 64; s += 256) {
        const int kb = s >> 6, l = s & 63;
        const int row = p * 16 + (l & 15);
        const int k0 = kb * 32 + ((l >> 4) << 3);
        const float* src = X + (ull)row * K + k0;
        u16x8 hi, mi;
        #pragma unroll
        for (int e = 0; e < 8; e++) {
            const float x = src[e];
            const unsigned short h = f2bf_rn(x);
            hi[e] = h;
            mi[e] = f2bf_rn(x - bf2f(h));
        }
        const ull o = (((ull)p * KB + kb) * 64 + l) * 8;
        *(u16x8*)&Phi[o] = hi;
        *(u16x8*)&Pmi[o] = mi;
    }
}

// ---- MFMA projection GEMM (bf16x3): C[M][256] fp32 = A @ B^T, K = KB*32 ----
__global__ __launch_bounds__(256)
void gemm_proj_mfma(const unsigned short* __restrict__ Ahi, const unsigned short* __restrict__ Ami,
                    const unsigned short* __restrict__ Bhi, const unsigned short* __restrict__ Bmi,
                    float* __restrict__ C, int N, int KB)
{
    const int l = threadIdx.x & 63;
    const int w = threadIdx.x >> 6;
    const int n0 = blockIdx.x * 64, m0 = blockIdx.y * 128;
    const int pA0 = (m0 >> 4) + w * 2;
    const int pB0 = n0 >> 4;
    f32x4 acc[2][4] = {};
    for (int kb = 0; kb < KB; kb++) {
        const ull a0o = (((ull)(pA0 + 0) * KB + kb) * 64 + l) * 8;
        const ull a1o = (((ull)(pA0 + 1) * KB + kb) * 64 + l) * 8;
        const bf16x8 aH0 = *(const bf16x8*)&Ahi[a0o];
        const bf16x8 aM0 = *(const bf16x8*)&Ami[a0o];
        const bf16x8 aH1 = *(const bf16x8*)&Ahi[a1o];
        const bf16x8 aM1 = *(const bf16x8*)&Ami[a1o];
        #pragma unroll
        for (int j = 0; j < 4; j++) {
            const ull bo = (((ull)(pB0 + j) * KB + kb) * 64 + l) * 8;
            const bf16x8 bH = *(const bf16x8*)&Bhi[bo];
            const bf16x8 bM = *(const bf16x8*)&Bmi[bo];
            acc[0][j] = __builtin_amdgcn_mfma_f32_16x16x32_bf16(aH0, bH, acc[0][j], 0, 0, 0);
            acc[0][j] = __builtin_amdgcn_mfma_f32_16x16x32_bf16(aH0, bM, acc[0][j], 0, 0, 0);
            acc[0][j] = __builtin_amdgcn_mfma_f32_16x16x32_bf16(aM0, bH, acc[0][j], 0, 0, 0);
            acc[1][j] = __builtin_amdgcn_mfma_f32_16x16x32_bf16(aH1, bH, acc[1][j], 0, 0, 0);
            acc[1][j] = __builtin_amdgcn_mfma_f32_16x16x32_bf16(aH1, bM, acc[1][j], 0, 0, 0);
            acc[1][j] = __builtin_amdgcn_mfma_f32_16x16x32_bf16(aM1, bH, acc[1][j], 0, 0, 0);
        }
    }
    // C/D layout (m89-verified): col = lane&15, row = (lane>>4)*4 + reg
    const int col = l & 15;
    #pragma unroll
    for (int i = 0; i < 2; i++) {
        const int row0 = m0 + w * 32 + i * 16 + ((l >> 4) << 2);
        #pragma unroll
        for (int r = 0; r < 4; r++) {
            const ull rowb = (ull)(row0 + r) * N + n0;
            #pragma unroll
            for (int j = 0; j < 4; j++)
                C[rowb + j * 16 + col] = acc[i][j][r];
        }
    }
}

// ---- MFMA cost GEMM (bf16x3 split), 128x64 block tile, 2 A-panels/wave ----
__device__ __forceinline__ unsigned int quant16(float c, float s) {
    return __float2uint_rn(fminf(c * s, 65535.0f));
}

__global__ __launch_bounds__(256)
void gemm_cost_mfma(const unsigned short* __restrict__ Ahi, const unsigned short* __restrict__ Ami,
                    const unsigned short* __restrict__ Bhi, const unsigned short* __restrict__ Bmi,
                    unsigned short* __restrict__ C,
                    const float* __restrict__ na, const float* __restrict__ nb,
                    const float* __restrict__ qsp, int N)
{
    const int l = threadIdx.x & 63;
    const int w = threadIdx.x >> 6;
    const int n0 = blockIdx.x * 64, m0 = blockIdx.y * 128;
    const int pA0 = (m0 >> 4) + w * 2;   // 2 A panels per wave (32 rows)
    const int pB0 = n0 >> 4;
    f32x4 acc[2][4] = {};
    #pragma unroll
    for (int kb = 0; kb < 8; kb++) {
        const ull a0o = (((ull)(pA0 + 0) * 8 + kb) * 64 + l) * 8;
        const ull a1o = (((ull)(pA0 + 1) * 8 + kb) * 64 + l) * 8;
        const bf16x8 aH0 = *(const bf16x8*)&Ahi[a0o];
        const bf16x8 aM0 = *(const bf16x8*)&Ami[a0o];
        const bf16x8 aH1 = *(const bf16x8*)&Ahi[a1o];
        const bf16x8 aM1 = *(const bf16x8*)&Ami[a1o];
        #pragma unroll
        for (int j = 0; j < 4; j++) {
            const ull bo = (((ull)(pB0 + j) * 8 + kb) * 64 + l) * 8;
            const bf16x8 bH = *(const bf16x8*)&Bhi[bo];
            const bf16x8 bM = *(const bf16x8*)&Bmi[bo];
            acc[0][j] = __builtin_amdgcn_mfma_f32_16x16x32_bf16(aH0, bH, acc[0][j], 0, 0, 0);
            acc[0][j] = __builtin_amdgcn_mfma_f32_16x16x32_bf16(aH0, bM, acc[0][j], 0, 0, 0);
            acc[0][j] = __builtin_amdgcn_mfma_f32_16x16x32_bf16(aM0, bH, acc[0][j], 0, 0, 0);
            acc[1][j] = __builtin_amdgcn_mfma_f32_16x16x32_bf16(aH1, bH, acc[1][j], 0, 0, 0);
            acc[1][j] = __builtin_amdgcn_mfma_f32_16x16x32_bf16(aH1, bM, acc[1][j], 0, 0, 0);
            acc[1][j] = __builtin_amdgcn_mfma_f32_16x16x32_bf16(aM1, bH, acc[1][j], 0, 0, 0);
        }
    }
    // C/D layout (m89-verified): col = lane&15, row = (lane>>4)*4 + reg
    const float s = qsp[0];
    const int col = l & 15;
    float nbj[4];
    #pragma unroll
    for (int j = 0; j < 4; j++) nbj[j] = nb[n0 + j * 16 + col];
    #pragma unroll
    for (int i = 0; i < 2; i++) {
        const int row0 = m0 + w * 32 + i * 16 + ((l >> 4) << 2);
        #pragma unroll
        for (int r = 0; r < 4; r++) {
            const float nar = na[row0 + r];
            const ull rowb = (ull)(row0 + r) * N + n0;
            #pragma unroll
            for (int j = 0; j < 4; j++)
                C[rowb + j * 16 + col] =
                    (unsigned short)quant16(0.5f * fmaxf(nar + nbj[j] - 2.0f * acc[i][j][r], 0.0f), s);
        }
    }
}

// ---- row squared-norms ----
__global__ __launch_bounds__(256)
void row_norm(const float* __restrict__ x, float* __restrict__ o)
{
    const int i = blockIdx.x;
    const float v = x[(size_t)i * DOUT + threadIdx.x];
    float s = wave_sum(v * v);
    __shared__ float red[4];
    const int wid = threadIdx.x >> 6, lane = threadIdx.x & 63;
    if (lane == 0) red[wid] = s;
    __syncthreads();
    if (threadIdx.x == 0) o[i] = red[0] + red[1] + red[2] + red[3];
}

// ---- per-column min/max partials ----
__global__ __launch_bounds__(256)
void colminmax_k(const float* __restrict__ xd, const float* __restrict__ x1,
                 const float* __restrict__ x2, float* __restrict__ ws)
{
    const int b = blockIdx.x, c = threadIdx.x;
    const float* src; int r0;
    if (b < 64)      { src = xd; r0 = b * 64; }
    else if (b < 80) { src = x1; r0 = (b - 64) * 64; }
    else             { src = x2; r0 = (b - 80) * 64; }
    float mn = 3.4e38f, mx = -3.4e38f;
    for (int r = 0; r < 64; r++) {
        const float v = src[(size_t)(r0 + r) * DOUT + c];
        mn = fminf(mn, v); mx = fmaxf(mx, v);
    }
    ws[O_PMIN + (ull)b * 256 + c] = mn;
    ws[O_PMAX + (ull)b * 256 + c] = mx;
}

// ---- partials -> diam -> eps schedule + quant scale ----
__global__ __launch_bounds__(256)
void eps_k(float* __restrict__ ws)
{
    const int c = threadIdx.x;
    const float* pmin = ws + O_PMIN;
    const float* pmax = ws + O_PMAX;
    float mnd = 3.4e38f, mxd = -3.4e38f;
    float mn1 = 3.4e38f, mx1 = -3.4e38f;
    float mn2 = 3.4e38f, mx2 = -3.4e38f;
    for (int b = 0;  b < 64; b++) { mnd = fminf(mnd, pmin[b*256+c]); mxd = fmaxf(mxd, pmax[b*256+c]); }
    for (int b = 64; b < 80; b++) { mn1 = fminf(mn1, pmin[b*256+c]); mx1 = fmaxf(mx1, pmax[b*256+c]); }
    for (int b = 80; b < 96; b++) { mn2 = fminf(mn2, pmin[b*256+c]); mx2 = fmaxf(mx2, pmax[b*256+c]); }
    const float d1 = fmaxf(mxd, mx1) - fminf(mnd, mn1);
    const float d2 = fmaxf(mxd, mx2) - fminf(mnd, mn2);
    float s1 = wave_sum(d1 * d1);
    float s2 = wave_sum(d2 * d2);
    __shared__ float r1[4], r2[4];
    const int wid = c >> 6, lane = c & 63;
    if (lane == 0) { r1[wid] = s1; r2[wid] = s2; }
    __syncthreads();
    if (c == 0) {
        const float d1s = r1[0]+r1[1]+r1[2]+r1[3];
        const float d2s = r2[0]+r2[1]+r2[2]+r2[3];
        const float cb = 0.5f * fmaxf(d1s, d2s) * 1.02f + 1.0f;
        ws[O_QS]     = 65535.0f / cb;
        ws[O_QS + 1] = cb / 65535.0f;
    }
    if (c < 2 * NIT) {
        const int div = c / NIT, tt = c % NIT;
        const float ss = div ? (r2[0]+r2[1]+r2[2]+r2[3]) : (r1[0]+r1[1]+r1[2]+r1[3]);
        const float diam = sqrtf(ss) + 1e-6f;
        const float sc = fmaxf(0.5f, diam * powf(0.8f, (float)tt));
        ws[O_EPS + (ull)div * NIT + tt] = sc * sc;
    }
}

// ---- wave-per-row stable softmin over a u16-quantized row (r4/r8 proven) ----
template<int NC>   // NC x 512-element chunks
__device__ __forceinline__ void softmin_row_q(
    const unsigned short* __restrict__ Crow, const float* __restrict__ hvec,
    float hc2, float eps, float qs,
    const float* __restrict__ selfv, float* __restrict__ outp,
    int row, int phase, int lane)
{
    const float ie2 = LOG2E / eps;
    const float qsc = -qs * ie2;
    const u16x8* Q8 = (const u16x8*)Crow;
    const float4* H4 = (const float4*)hvec;
    float v[NC * 8];
    #pragma unroll
    for (int c = 0; c < NC; c++) {
        const u16x8 q = Q8[c * 64 + lane];
        if (hvec) {
            const float4 ha = H4[c * 128 + lane * 2];
            const float4 hb = H4[c * 128 + lane * 2 + 1];
            const float hv[8] = {ha.x, ha.y, ha.z, ha.w, hb.x, hb.y, hb.z, hb.w};
            #pragma unroll
            for (int e = 0; e < 8; e++)
                v[c*8 + e] = fmaf((float)q[e], qsc, fmaf(hv[e], ie2, hc2));
        } else {
            #pragma unroll
            for (int e = 0; e < 8; e++)
                v[c*8 + e] = fmaf((float)q[e], qsc, hc2);
        }
    }
    float m = v[0];
    #pragma unroll
    for (int k = 1; k < NC * 8; k++) m = fmaxf(m, v[k]);
    m = wave_max(m);
    float s = 0.0f;
    #pragma unroll
    for (int k = 0; k < NC * 8; k++) s += exp2f(v[k] - m);
    s = wave_sum(s);
    if (lane == 0) {
        float res = -eps * LN2 * (m + log2f(s));
        if (phase == 1) res = 0.5f * (selfv[row] + res);
        outp[row] = res;
    }
}

// ---- fused Sinkhorn step: r4/r8 proven map (16384 waves, 4096 blocks) ----
//  [0,8192)      ft   (C_xy rows, len 1024), div = w>>12
//  [8192,10240)  gt   (C_yx rows, len 4096), div = (w-8192)>>10
//  [10240,14336) f_aa (C_xx rows), both divergences sequentially (row L1-hot)
//  [14336,16384) g_bb (C_yy rows, len 1024), div = (w-14336)>>10
__global__ __launch_bounds__(256)
void sinkhorn_phase(float* __restrict__ ws, int phase, int t)
{
    const unsigned short* uq = (const unsigned short*)ws;
    const int wid = threadIdx.x >> 6, lane = threadIdx.x & 63;
    const int w = blockIdx.x * 4 + wid;
    const float qs = ws[O_QS + 1];
    int rb, wb;
    if (phase == 0) { rb = 0; wb = 0; }
    else { rb = t & 1; wb = rb ^ 1; }   // phase 2 passes t=36 -> rb=0

    if (w < 8192) {                       // ft -> f_ab
        const int div = w >> 12, i = w & 4095;
        const float eps = (phase == 2) ? 0.25f : ws[O_EPS + (ull)div * NIT + t];
        const unsigned short* Crow = uq + U_CXY + (ull)div * ND * NS + (ull)i * NS;
        const float* gab_r = ws + O_GAB + ((ull)div * 2 + rb) * NS;
        const float* fab_r = ws + O_FAB + ((ull)div * 2 + rb) * ND;
        float* outp = (phase == 2) ? (ws + O_FABN + (ull)div * ND)
                                   : (ws + O_FAB + ((ull)div * 2 + wb) * ND);
        softmin_row_q<2>(Crow, phase ? gab_r : nullptr, B_LOG2, eps, qs, fab_r, outp, i, phase, lane);
    } else if (w < 10240) {               // gt -> g_ab
        const int q = w - 8192, div = q >> 10, j = q & 1023;
        const float eps = (phase == 2) ? 0.25f : ws[O_EPS + (ull)div * NIT + t];
        const unsigned short* Crow = uq + U_CYX + (ull)div * ND * NS + (ull)j * ND;
        const float* fab_r = ws + O_FAB + ((ull)div * 2 + rb) * ND;
        const float* gab_r = ws + O_GAB + ((ull)div * 2 + rb) * NS;
        float* outp = (phase == 2) ? (ws + O_GABN + (ull)div * NS)
                                   : (ws + O_GAB + ((ull)div * 2 + wb) * NS);
        softmin_row_q<8>(Crow, phase ? fab_r : nullptr, A_LOG2, eps, qs, gab_r, outp, j, phase, lane);
    } else if (w < 14336) {               // f_aa, both divergences sequentially
        const int i = w - 10240;
        const float eps0 = (phase == 2) ? 0.25f : ws[O_EPS + t];
        const float eps1 = (phase == 2) ? 0.25f : ws[O_EPS + NIT + t];
        const unsigned short* Crow = uq + U_CXX + (ull)i * ND;
        const float* faa_r0 = ws + O_FAA + (ull)rb * ND;
        const float* faa_r1 = ws + O_FAA + (2ull + rb) * ND;
        float* out0 = (phase == 2) ? (ws + O_FAAN)      : (ws + O_FAA + (ull)wb * ND);
        float* out1 = (phase == 2) ? (ws + O_FAAN + ND) : (ws + O_FAA + (2ull + wb) * ND);
        softmin_row_q<8>(Crow, phase ? faa_r0 : nullptr, A_LOG2, eps0, qs, faa_r0, out0, i, phase, lane);
        softmin_row_q<8>(Crow, phase ? faa_r1 : nullptr, A_LOG2, eps1, qs, faa_r1, out1, i, phase, lane);
    } else {                              // g_bb
        const int q = w - 14336, div = q >> 10, i = q & 1023;
        const float eps = (phase == 2) ? 0.25f : ws[O_EPS + (ull)div * NIT + t];
        const unsigned short* Crow = uq + U_CYY + (ull)div * NS * NS + (ull)i * NS;
        const float* gbb_r = ws + O_GBB + ((ull)div * 2 + rb) * NS;
        float* outp = (phase == 2) ? (ws + O_GBBN + (ull)div * NS)
                                   : (ws + O_GBB + ((ull)div * 2 + wb) * NS);
        softmin_row_q<2>(Crow, phase ? gbb_r : nullptr, B_LOG2, eps, qs, gbb_r, outp, i, phase, lane);
    }
}

// ---- dist[d] = mean(f_ab_n - f_aa_n) + mean(g_ab_n - g_bb_n) ----
__global__ __launch_bounds__(256)
void reduce_dist(float* __restrict__ ws)
{
    const int d = blockIdx.x;
    const int tix = threadIdx.x;
    float s = 0.0f;
    #pragma unroll
    for (int k = 0; k < 16; k++) {
        const int i = tix + k * 256;
        s += (ws[O_FABN + (ull)d * ND + i] - ws[O_FAAN + (ull)d * ND + i]) * (1.0f / 4096.0f);
    }
    #pragma unroll
    for (int k = 0; k < 4; k++) {
        const int j = tix + k * 256;
        s += (ws[O_GABN + (ull)d * NS + j] - ws[O_GBBN + (ull)d * NS + j]) * (1.0f / 1024.0f);
    }
    s = wave_sum(s);
    __shared__ float red[4];
    const int wid = tix >> 6, lane = tix & 63;
    if (lane == 0) red[wid] = s;
    __syncthreads();
    if (tix == 0) ws[O_DIST + d] = red[0] + red[1] + red[2] + red[3];
}

__global__ void finalize_k(const float* __restrict__ ws, float* __restrict__ out)
{
    const float x = ws[O_DIST + 1] - ws[O_DIST + 0];   // dist2 - dist1
    out[0] = 1.0f / (1.0f + expf(-x));
}

extern "C" void kernel_launch(void* const* d_in, const int* in_sizes, int n_in,
                              void* d_out, int out_size, void* d_ws, size_t ws_size,
                              hipStream_t stream)
{
    if (ws_size < WS_FLOATS * sizeof(float)) return;   // ~105 MB required

    const float* dmat = (const float*)d_in[0];
    const float* s1   = (const float*)d_in[1];
    const float* s2   = (const float*)d_in[2];
    const float* M    = (const float*)d_in[3];
    float* ws  = (float*)d_ws;
    float* out = (float*)d_out;
    unsigned short* uq = (unsigned short*)d_ws;

    float* Mt = ws + O_MT;
    float* xd = ws + O_XD;
    float* x1 = ws + O_X1;
    float* x2 = ws + O_X2;

    // pack raw inputs (K=768) into MFMA fragment order, bf16 hi/mid
    transpose_M_k<<<768, 256, 0, stream>>>(M, Mt);
    pack_bf16_gen<<<256, 256, 0, stream>>>(dmat, uq + P_DH,  uq + P_DM,  24);
    pack_bf16_gen<<<64,  256, 0, stream>>>(s1,   uq + P_S1H, uq + P_S1M, 24);
    pack_bf16_gen<<<64,  256, 0, stream>>>(s2,   uq + P_S2H, uq + P_S2M, 24);
    pack_bf16_gen<<<16,  256, 0, stream>>>(Mt,   uq + P_MTH, uq + P_MTM, 24);
    // projections via MFMA (bf16x3), fp32 outputs
    gemm_proj_mfma<<<dim3(4, 32), 256, 0, stream>>>(uq+P_DH,  uq+P_DM,  uq+P_MTH, uq+P_MTM, xd, 256, 24);
    gemm_proj_mfma<<<dim3(4, 8),  256, 0, stream>>>(uq+P_S1H, uq+P_S1M, uq+P_MTH, uq+P_MTM, x1, 256, 24);
    gemm_proj_mfma<<<dim3(4, 8),  256, 0, stream>>>(uq+P_S2H, uq+P_S2M, uq+P_MTH, uq+P_MTM, x2, 256, 24);
    row_norm<<<4096, 256, 0, stream>>>(xd, ws + O_ND_);
    row_norm<<<1024, 256, 0, stream>>>(x1, ws + O_N1);
    row_norm<<<1024, 256, 0, stream>>>(x2, ws + O_N2);
    colminmax_k<<<96, 256, 0, stream>>>(xd, x1, x2, ws);   // overwrites dead Mt
    eps_k<<<1, 256, 0, stream>>>(ws);
    // pack projected coords (K=256) for cost GEMMs
    pack_bf16_gen<<<256, 256, 0, stream>>>(xd, uq + P_XDH, uq + P_XDM, 8);
    pack_bf16_gen<<<64,  256, 0, stream>>>(x1, uq + P_X1H, uq + P_X1M, 8);
    pack_bf16_gen<<<64,  256, 0, stream>>>(x2, uq + P_X2H, uq + P_X2M, 8);
    // cost matrices via MFMA (bf16x3, 128x64 tile); CT as swapped-operand GEMMs
    const float* qsp = ws + O_QS;
    const float* nd_ = ws + O_ND_;
    const float* n1  = ws + O_N1;
    const float* n2  = ws + O_N2;
    gemm_cost_mfma<<<dim3(64, 32), 256, 0, stream>>>(uq+P_XDH, uq+P_XDM, uq+P_XDH, uq+P_XDM, uq + U_CXX,         nd_, nd_, qsp, 4096);
    gemm_cost_mfma<<<dim3(16, 32), 256, 0, stream>>>(uq+P_XDH, uq+P_XDM, uq+P_X1H, uq+P_X1M, uq + U_CXY,         nd_, n1,  qsp, 1024);
    gemm_cost_mfma<<<dim3(64, 8),  256, 0, stream>>>(uq+P_X1H, uq+P_X1M, uq+P_XDH, uq+P_XDM, uq + U_CYX,         n1,  nd_, qsp, 4096);
    gemm_cost_mfma<<<dim3(16, 32), 256, 0, stream>>>(uq+P_XDH, uq+P_XDM, uq+P_X2H, uq+P_X2M, uq + U_CXY + ND*NS, nd_, n2,  qsp, 1024);
    gemm_cost_mfma<<<dim3(64, 8),  256, 0, stream>>>(uq+P_X2H, uq+P_X2M, uq+P_XDH, uq+P_XDM, uq + U_CYX + ND*NS, n2,  nd_, qsp, 4096);
    gemm_cost_mfma<<<dim3(16, 8),  256, 0, stream>>>(uq+P_X1H, uq+P_X1M, uq+P_X1H, uq+P_X1M, uq + U_CYY,         n1,  n1,  qsp, 1024);
    gemm_cost_mfma<<<dim3(16, 8),  256, 0, stream>>>(uq+P_X2H, uq+P_X2M, uq+P_X2H, uq+P_X2M, uq + U_CYY + NS*NS, n2,  n2,  qsp, 1024);
    // Sinkhorn loop: r8 proven shape (16384 waves, multi-launch barriers)
    sinkhorn_phase<<<4096, 256, 0, stream>>>(ws, 0, 0);
    for (int t = 0; t < NIT; t++)
        sinkhorn_phase<<<4096, 256, 0, stream>>>(ws, 1, t);
    sinkhorn_phase<<<4096, 256, 0, stream>>>(ws, 2, 36);
    reduce_dist<<<2, 256, 0, stream>>>(ws);
    finalize_k<<<1, 1, 0, stream>>>(ws, out);
}

// Round 12
// 1289.297 us; speedup vs baseline: 1.7833x; 1.1099x over previous
//
#include <hip/hip_runtime.h>
#include <hip/hip_bf16.h>
#include <math.h>

using ull = unsigned long long;
typedef unsigned short u16x8 __attribute__((ext_vector_type(8)));
typedef __attribute__((ext_vector_type(8))) short bf16x8;   // 8 bf16 (4 VGPRs)
typedef __attribute__((ext_vector_type(4))) float f32x4;

// Problem constants
#define ND 4096ull   // n (xd rows)
#define NS 1024ull   // m (s1/s2 rows)
#define DOUT 256ull
#define DIN 768ull
#define NIT 36

// ---- u16 regions (ushort offsets into ws) ----
constexpr ull U_CXX = 0;                 // [ND*ND], shared by both divergences
constexpr ull U_CXY = U_CXX + ND*ND;     // [2][ND*NS]
constexpr ull U_CYX = U_CXY + 2*ND*NS;   // [2][NS*ND] transposed copies
constexpr ull U_CYY = U_CYX + 2*ND*NS;   // [2][NS*NS]
constexpr ull U_TOT = U_CYY + 2*NS*NS;   // ~71.3 MB
// bf16 hi/mid packed fragment buffers for cost GEMMs (K=256)
constexpr ull P_XDH = U_TOT;
constexpr ull P_XDM = P_XDH + ND*DOUT;
constexpr ull P_X1H = P_XDM + ND*DOUT;
constexpr ull P_X1M = P_X1H + NS*DOUT;
constexpr ull P_X2H = P_X1M + NS*DOUT;
constexpr ull P_X2M = P_X2H + NS*DOUT;
// bf16 hi/mid packed fragment buffers for projection GEMMs (K=768)
constexpr ull P_DH  = P_X2M + NS*DOUT;
constexpr ull P_DM  = P_DH + ND*DIN;
constexpr ull P_S1H = P_DM + ND*DIN;
constexpr ull P_S1M = P_S1H + NS*DIN;
constexpr ull P_S2H = P_S1M + NS*DIN;
constexpr ull P_S2M = P_S2H + NS*DIN;
constexpr ull P_MTH = P_S2M + NS*DIN;
constexpr ull P_MTM = P_MTH + DOUT*DIN;
constexpr ull U_END = P_MTM + DOUT*DIN;  // even

// ---- fp32 region (float offsets into ws) ----
constexpr ull O_XD   = U_END / 2;
constexpr ull O_X1   = O_XD + ND*DOUT;
constexpr ull O_X2   = O_X1 + NS*DOUT;
constexpr ull O_MT   = O_X2 + NS*DOUT;       // [DOUT*DIN], dead after Mt pack
constexpr ull O_ND_  = O_MT + DOUT*DIN;
constexpr ull O_N1   = O_ND_ + ND;
constexpr ull O_N2   = O_N1 + NS;
constexpr ull O_FAB  = O_N2 + NS;            // [2 div][2 buf][ND]
constexpr ull O_GAB  = O_FAB + 4*ND;         // [2][2][NS]
constexpr ull O_FAA  = O_GAB + 4*NS;         // [2][2][ND]
constexpr ull O_GBB  = O_FAA + 4*ND;         // [2][2][NS]
constexpr ull O_FABN = O_GBB + 4*NS;         // [2][ND]
constexpr ull O_GABN = O_FABN + 2*ND;        // [2][NS]
constexpr ull O_FAAN = O_GABN + 2*NS;        // [2][ND]
constexpr ull O_GBBN = O_FAAN + 2*ND;        // [2][NS]
constexpr ull O_EPS  = O_GBBN + 2*NS;        // [2][NIT]
constexpr ull O_QS   = O_EPS + 2*NIT;        // [0]=quant scale, [1]=dequant
constexpr ull O_DIST = O_QS + 2;             // [2]
constexpr ull WS_FLOATS = O_DIST + 2;        // ~105 MB total
// diameter partials reuse dead Mt region (after Mt is packed)
constexpr ull O_PMIN = O_MT;                 // [96*256]
constexpr ull O_PMAX = O_MT + 96*256;        // [96*256]

constexpr float LOG2E = 1.4426950408889634f;
constexpr float LN2   = 0.69314718055994531f;
constexpr float A_LOG2 = -12.0f;   // -log2(4096)
constexpr float B_LOG2 = -10.0f;   // -log2(1024)

__device__ __forceinline__ float wave_max(float v) {
    #pragma unroll
    for (int o = 32; o; o >>= 1) v = fmaxf(v, __shfl_xor(v, o));
    return v;
}
__device__ __forceinline__ float wave_sum(float v) {
    #pragma unroll
    for (int o = 32; o; o >>= 1) v += __shfl_xor(v, o);
    return v;
}

__device__ __forceinline__ unsigned short f2bf_rn(float x) {
    union { float f; unsigned u; } v; v.f = x;
    const unsigned r = v.u + 0x7FFFu + ((v.u >> 16) & 1u);
    return (unsigned short)(r >> 16);
}
__device__ __forceinline__ float bf2f(unsigned short b) {
    union { unsigned u; float f; } v; v.u = ((unsigned)b) << 16; return v.f;
}

// ---- transpose M [DIN x DOUT] -> Mt [DOUT x DIN] ----
__global__ __launch_bounds__(256)
void transpose_M_k(const float* __restrict__ M, float* __restrict__ Mt)
{
    int idx = blockIdx.x * 256 + threadIdx.x;
    int r = idx >> 8;
    int c = idx & 255;
    Mt[(size_t)c * DIN + r] = M[idx];
}

// ---- pack fp32 [R][KB*32] -> bf16 hi/mid in MFMA fragment order ----
// slot(p,kb,l,e) = ((p*KB+kb)*64+l)*8+e  holds  X[p*16+(l&15)][kb*32+(l>>4)*8+e]
__global__ __launch_bounds__(256)
void pack_bf16_gen(const float* __restrict__ X,
                   unsigned short* __restrict__ Phi, unsigned short* __restrict__ Pmi,
                   int KB)
{
    const int p = blockIdx.x;
    const int t = threadIdx.x;
    const int K = KB * 32;
    for (int s = t; s < KB * 64; s += 256) {
        const int kb = s >> 6, l = s & 63;
        const int row = p * 16 + (l & 15);
        const int k0 = kb * 32 + ((l >> 4) << 3);
        const float* src = X + (ull)row * K + k0;
        u16x8 hi, mi;
        #pragma unroll
        for (int e = 0; e < 8; e++) {
            const float x = src[e];
            const unsigned short h = f2bf_rn(x);
            hi[e] = h;
            mi[e] = f2bf_rn(x - bf2f(h));
        }
        const ull o = (((ull)p * KB + kb) * 64 + l) * 8;
        *(u16x8*)&Phi[o] = hi;
        *(u16x8*)&Pmi[o] = mi;
    }
}

// ---- MFMA projection GEMM (bf16x3): C[M][256] fp32 = A @ B^T, K = KB*32 ----
__global__ __launch_bounds__(256)
void gemm_proj_mfma(const unsigned short* __restrict__ Ahi, const unsigned short* __restrict__ Ami,
                    const unsigned short* __restrict__ Bhi, const unsigned short* __restrict__ Bmi,
                    float* __restrict__ C, int N, int KB)
{
    const int l = threadIdx.x & 63;
    const int w = threadIdx.x >> 6;
    const int n0 = blockIdx.x * 64, m0 = blockIdx.y * 128;
    const int pA0 = (m0 >> 4) + w * 2;
    const int pB0 = n0 >> 4;
    f32x4 acc[2][4] = {};
    for (int kb = 0; kb < KB; kb++) {
        const ull a0o = (((ull)(pA0 + 0) * KB + kb) * 64 + l) * 8;
        const ull a1o = (((ull)(pA0 + 1) * KB + kb) * 64 + l) * 8;
        const bf16x8 aH0 = *(const bf16x8*)&Ahi[a0o];
        const bf16x8 aM0 = *(const bf16x8*)&Ami[a0o];
        const bf16x8 aH1 = *(const bf16x8*)&Ahi[a1o];
        const bf16x8 aM1 = *(const bf16x8*)&Ami[a1o];
        #pragma unroll
        for (int j = 0; j < 4; j++) {
            const ull bo = (((ull)(pB0 + j) * KB + kb) * 64 + l) * 8;
            const bf16x8 bH = *(const bf16x8*)&Bhi[bo];
            const bf16x8 bM = *(const bf16x8*)&Bmi[bo];
            acc[0][j] = __builtin_amdgcn_mfma_f32_16x16x32_bf16(aH0, bH, acc[0][j], 0, 0, 0);
            acc[0][j] = __builtin_amdgcn_mfma_f32_16x16x32_bf16(aH0, bM, acc[0][j], 0, 0, 0);
            acc[0][j] = __builtin_amdgcn_mfma_f32_16x16x32_bf16(aM0, bH, acc[0][j], 0, 0, 0);
            acc[1][j] = __builtin_amdgcn_mfma_f32_16x16x32_bf16(aH1, bH, acc[1][j], 0, 0, 0);
            acc[1][j] = __builtin_amdgcn_mfma_f32_16x16x32_bf16(aH1, bM, acc[1][j], 0, 0, 0);
            acc[1][j] = __builtin_amdgcn_mfma_f32_16x16x32_bf16(aM1, bH, acc[1][j], 0, 0, 0);
        }
    }
    const int col = l & 15;
    #pragma unroll
    for (int i = 0; i < 2; i++) {
        const int row0 = m0 + w * 32 + i * 16 + ((l >> 4) << 2);
        #pragma unroll
        for (int r = 0; r < 4; r++) {
            const ull rowb = (ull)(row0 + r) * N + n0;
            #pragma unroll
            for (int j = 0; j < 4; j++)
                C[rowb + j * 16 + col] = acc[i][j][r];
        }
    }
}

// ---- MFMA cost GEMM (bf16x3 split), 128x64 block tile, 2 A-panels/wave ----
__device__ __forceinline__ unsigned int quant16(float c, float s) {
    return __float2uint_rn(fminf(c * s, 65535.0f));
}

__global__ __launch_bounds__(256)
void gemm_cost_mfma(const unsigned short* __restrict__ Ahi, const unsigned short* __restrict__ Ami,
                    const unsigned short* __restrict__ Bhi, const unsigned short* __restrict__ Bmi,
                    unsigned short* __restrict__ C,
                    const float* __restrict__ na, const float* __restrict__ nb,
                    const float* __restrict__ qsp, int N)
{
    const int l = threadIdx.x & 63;
    const int w = threadIdx.x >> 6;
    const int n0 = blockIdx.x * 64, m0 = blockIdx.y * 128;
    const int pA0 = (m0 >> 4) + w * 2;   // 2 A panels per wave (32 rows)
    const int pB0 = n0 >> 4;
    f32x4 acc[2][4] = {};
    #pragma unroll
    for (int kb = 0; kb < 8; kb++) {
        const ull a0o = (((ull)(pA0 + 0) * 8 + kb) * 64 + l) * 8;
        const ull a1o = (((ull)(pA0 + 1) * 8 + kb) * 64 + l) * 8;
        const bf16x8 aH0 = *(const bf16x8*)&Ahi[a0o];
        const bf16x8 aM0 = *(const bf16x8*)&Ami[a0o];
        const bf16x8 aH1 = *(const bf16x8*)&Ahi[a1o];
        const bf16x8 aM1 = *(const bf16x8*)&Ami[a1o];
        #pragma unroll
        for (int j = 0; j < 4; j++) {
            const ull bo = (((ull)(pB0 + j) * 8 + kb) * 64 + l) * 8;
            const bf16x8 bH = *(const bf16x8*)&Bhi[bo];
            const bf16x8 bM = *(const bf16x8*)&Bmi[bo];
            acc[0][j] = __builtin_amdgcn_mfma_f32_16x16x32_bf16(aH0, bH, acc[0][j], 0, 0, 0);
            acc[0][j] = __builtin_amdgcn_mfma_f32_16x16x32_bf16(aH0, bM, acc[0][j], 0, 0, 0);
            acc[0][j] = __builtin_amdgcn_mfma_f32_16x16x32_bf16(aM0, bH, acc[0][j], 0, 0, 0);
            acc[1][j] = __builtin_amdgcn_mfma_f32_16x16x32_bf16(aH1, bH, acc[1][j], 0, 0, 0);
            acc[1][j] = __builtin_amdgcn_mfma_f32_16x16x32_bf16(aH1, bM, acc[1][j], 0, 0, 0);
            acc[1][j] = __builtin_amdgcn_mfma_f32_16x16x32_bf16(aM1, bH, acc[1][j], 0, 0, 0);
        }
    }
    const float s = qsp[0];
    const int col = l & 15;
    float nbj[4];
    #pragma unroll
    for (int j = 0; j < 4; j++) nbj[j] = nb[n0 + j * 16 + col];
    #pragma unroll
    for (int i = 0; i < 2; i++) {
        const int row0 = m0 + w * 32 + i * 16 + ((l >> 4) << 2);
        #pragma unroll
        for (int r = 0; r < 4; r++) {
            const float nar = na[row0 + r];
            const ull rowb = (ull)(row0 + r) * N + n0;
            #pragma unroll
            for (int j = 0; j < 4; j++)
                C[rowb + j * 16 + col] =
                    (unsigned short)quant16(0.5f * fmaxf(nar + nbj[j] - 2.0f * acc[i][j][r], 0.0f), s);
        }
    }
}

// ---- row squared-norms ----
__global__ __launch_bounds__(256)
void row_norm(const float* __restrict__ x, float* __restrict__ o)
{
    const int i = blockIdx.x;
    const float v = x[(size_t)i * DOUT + threadIdx.x];
    float s = wave_sum(v * v);
    __shared__ float red[4];
    const int wid = threadIdx.x >> 6, lane = threadIdx.x & 63;
    if (lane == 0) red[wid] = s;
    __syncthreads();
    if (threadIdx.x == 0) o[i] = red[0] + red[1] + red[2] + red[3];
}

// ---- per-column min/max partials ----
__global__ __launch_bounds__(256)
void colminmax_k(const float* __restrict__ xd, const float* __restrict__ x1,
                 const float* __restrict__ x2, float* __restrict__ ws)
{
    const int b = blockIdx.x, c = threadIdx.x;
    const float* src; int r0;
    if (b < 64)      { src = xd; r0 = b * 64; }
    else if (b < 80) { src = x1; r0 = (b - 64) * 64; }
    else             { src = x2; r0 = (b - 80) * 64; }
    float mn = 3.4e38f, mx = -3.4e38f;
    for (int r = 0; r < 64; r++) {
        const float v = src[(size_t)(r0 + r) * DOUT + c];
        mn = fminf(mn, v); mx = fmaxf(mx, v);
    }
    ws[O_PMIN + (ull)b * 256 + c] = mn;
    ws[O_PMAX + (ull)b * 256 + c] = mx;
}

// ---- partials -> diam -> eps schedule + quant scale ----
__global__ __launch_bounds__(256)
void eps_k(float* __restrict__ ws)
{
    const int c = threadIdx.x;
    const float* pmin = ws + O_PMIN;
    const float* pmax = ws + O_PMAX;
    float mnd = 3.4e38f, mxd = -3.4e38f;
    float mn1 = 3.4e38f, mx1 = -3.4e38f;
    float mn2 = 3.4e38f, mx2 = -3.4e38f;
    for (int b = 0;  b < 64; b++) { mnd = fminf(mnd, pmin[b*256+c]); mxd = fmaxf(mxd, pmax[b*256+c]); }
    for (int b = 64; b < 80; b++) { mn1 = fminf(mn1, pmin[b*256+c]); mx1 = fmaxf(mx1, pmax[b*256+c]); }
    for (int b = 80; b < 96; b++) { mn2 = fminf(mn2, pmin[b*256+c]); mx2 = fmaxf(mx2, pmax[b*256+c]); }
    const float d1 = fmaxf(mxd, mx1) - fminf(mnd, mn1);
    const float d2 = fmaxf(mxd, mx2) - fminf(mnd, mn2);
    float s1 = wave_sum(d1 * d1);
    float s2 = wave_sum(d2 * d2);
    __shared__ float r1[4], r2[4];
    const int wid = c >> 6, lane = c & 63;
    if (lane == 0) { r1[wid] = s1; r2[wid] = s2; }
    __syncthreads();
    if (c == 0) {
        const float d1s = r1[0]+r1[1]+r1[2]+r1[3];
        const float d2s = r2[0]+r2[1]+r2[2]+r2[3];
        const float cb = 0.5f * fmaxf(d1s, d2s) * 1.02f + 1.0f;
        ws[O_QS]     = 65535.0f / cb;
        ws[O_QS + 1] = cb / 65535.0f;
    }
    if (c < 2 * NIT) {
        const int div = c / NIT, tt = c % NIT;
        const float ss = div ? (r2[0]+r2[1]+r2[2]+r2[3]) : (r1[0]+r1[1]+r1[2]+r1[3]);
        const float diam = sqrtf(ss) + 1e-6f;
        const float sc = fmaxf(0.5f, diam * powf(0.8f, (float)tt));
        ws[O_EPS + (ull)div * NIT + tt] = sc * sc;
    }
}

// ---- 1024-element softmin segment: returns wave-reduced partial (m, s) ----
__device__ __forceinline__ void softmin_1k(
    const unsigned short* __restrict__ Cseg, const float* __restrict__ hseg,
    float hc2, float ie2, float qsc, int lane, float& mO, float& sO)
{
    float v[16];
    #pragma unroll
    for (int c = 0; c < 2; c++) {
        const int off = c * 512 + lane * 8;
        const u16x8 q = *(const u16x8*)&Cseg[off];
        if (hseg) {
            const float4 ha = *(const float4*)&hseg[off];
            const float4 hb = *(const float4*)&hseg[off + 4];
            const float hv[8] = {ha.x, ha.y, ha.z, ha.w, hb.x, hb.y, hb.z, hb.w};
            #pragma unroll
            for (int e = 0; e < 8; e++)
                v[c*8 + e] = fmaf((float)q[e], qsc, fmaf(hv[e], ie2, hc2));
        } else {
            #pragma unroll
            for (int e = 0; e < 8; e++)
                v[c*8 + e] = fmaf((float)q[e], qsc, hc2);
        }
    }
    float m = v[0];
    #pragma unroll
    for (int k = 1; k < 16; k++) m = fmaxf(m, v[k]);
    m = wave_max(m);
    float s = 0.0f;
    #pragma unroll
    for (int k = 0; k < 16; k++) s += exp2f(v[k] - m);
    sO = wave_sum(s);
    mO = m;
}

// ---- fused Sinkhorn step: 51200 uniform waves (12800 blocks x 4) ----
// Every wave processes exactly 1024 C elements. Long rows split 4-way and
// combined via LDS (exact log-sum-exp merge).
// block map:
//  [0,2048)       ft   4 short rows/block (wave w -> row), div = b>>10
//  [2048,4096)    gt   1 long row split across 4 waves, div = (b-2048)>>10
//  [4096,12288)   faa  1 C_xx row x 1 div split across 4 waves
//  [12288,12800)  g_bb 4 short rows/block, div = (b-12288)>>8
__global__ __launch_bounds__(256)
void sinkhorn_phase(float* __restrict__ ws, int phase, int t)
{
    __shared__ float mS[4], sS[4];
    const unsigned short* uq = (const unsigned short*)ws;
    const int wid = threadIdx.x >> 6, lane = threadIdx.x & 63;
    const float qs = ws[O_QS + 1];
    int rb, wb;
    if (phase == 0) { rb = 0; wb = 0; }
    else { rb = t & 1; wb = rb ^ 1; }   // phase 2 passes t=36 -> rb=0
    const int b = blockIdx.x;

    if (b < 2048) {                       // ft -> f_ab : 4 rows, 1 per wave
        const int div = b >> 10;
        const int i = ((b & 1023) << 2) + wid;
        const float eps = (phase == 2) ? 0.25f : ws[O_EPS + (ull)div * NIT + t];
        const float ie2 = LOG2E / eps, qsc = -qs * ie2;
        const unsigned short* Crow = uq + U_CXY + (ull)div * ND * NS + (ull)i * NS;
        const float* h    = phase ? (ws + O_GAB + ((ull)div * 2 + rb) * NS) : nullptr;
        const float* self = ws + O_FAB + ((ull)div * 2 + rb) * ND;
        float* outp = (phase == 2) ? (ws + O_FABN + (ull)div * ND)
                                   : (ws + O_FAB + ((ull)div * 2 + wb) * ND);
        float m, s;
        softmin_1k(Crow, h, B_LOG2, ie2, qsc, lane, m, s);
        if (lane == 0) {
            float res = -eps * LN2 * (m + log2f(s));
            if (phase == 1) res = 0.5f * (self[i] + res);
            outp[i] = res;
        }
    } else if (b < 4096) {                // gt -> g_ab : 1 row / 4 waves
        const int q = b - 2048, div = q >> 10, j = q & 1023;
        const float eps = (phase == 2) ? 0.25f : ws[O_EPS + (ull)div * NIT + t];
        const float ie2 = LOG2E / eps, qsc = -qs * ie2;
        const unsigned short* Cseg = uq + U_CYX + (ull)div * ND * NS + (ull)j * ND + wid * 1024;
        const float* h    = phase ? (ws + O_FAB + ((ull)div * 2 + rb) * ND + wid * 1024) : nullptr;
        const float* self = ws + O_GAB + ((ull)div * 2 + rb) * NS;
        float* outp = (phase == 2) ? (ws + O_GABN + (ull)div * NS)
                                   : (ws + O_GAB + ((ull)div * 2 + wb) * NS);
        float m, s;
        softmin_1k(Cseg, h, A_LOG2, ie2, qsc, lane, m, s);
        if (lane == 0) { mS[wid] = m; sS[wid] = s; }
        __syncthreads();
        if (threadIdx.x == 0) {
            const float m0 = fmaxf(fmaxf(mS[0], mS[1]), fmaxf(mS[2], mS[3]));
            const float st = sS[0]*exp2f(mS[0]-m0) + sS[1]*exp2f(mS[1]-m0)
                           + sS[2]*exp2f(mS[2]-m0) + sS[3]*exp2f(mS[3]-m0);
            float res = -eps * LN2 * (m0 + log2f(st));
            if (phase == 1) res = 0.5f * (self[j] + res);
            outp[j] = res;
        }
    } else if (b < 12288) {               // f_aa : 1 row x 1 div / 4 waves
        const int q = b - 4096, div = q >> 12, i = q & 4095;
        const float eps = (phase == 2) ? 0.25f : ws[O_EPS + (ull)div * NIT + t];
        const float ie2 = LOG2E / eps, qsc = -qs * ie2;
        const unsigned short* Cseg = uq + U_CXX + (ull)i * ND + wid * 1024;
        const float* hbase = ws + O_FAA + ((ull)div * 2 + rb) * ND;
        const float* h = phase ? (hbase + wid * 1024) : nullptr;
        float* outp = (phase == 2) ? (ws + O_FAAN + (ull)div * ND)
                                   : (ws + O_FAA + ((ull)div * 2 + wb) * ND);
        float m, s;
        softmin_1k(Cseg, h, A_LOG2, ie2, qsc, lane, m, s);
        if (lane == 0) { mS[wid] = m; sS[wid] = s; }
        __syncthreads();
        if (threadIdx.x == 0) {
            const float m0 = fmaxf(fmaxf(mS[0], mS[1]), fmaxf(mS[2], mS[3]));
            const float st = sS[0]*exp2f(mS[0]-m0) + sS[1]*exp2f(mS[1]-m0)
                           + sS[2]*exp2f(mS[2]-m0) + sS[3]*exp2f(mS[3]-m0);
            float res = -eps * LN2 * (m0 + log2f(st));
            if (phase == 1) res = 0.5f * (hbase[i] + res);
            outp[i] = res;
        }
    } else {                              // g_bb : 4 rows, 1 per wave
        const int q = b - 12288, div = q >> 8;
        const int i = ((q & 255) << 2) + wid;
        const float eps = (phase == 2) ? 0.25f : ws[O_EPS + (ull)div * NIT + t];
        const float ie2 = LOG2E / eps, qsc = -qs * ie2;
        const unsigned short* Crow = uq + U_CYY + (ull)div * NS * NS + (ull)i * NS;
        const float* hb = ws + O_GBB + ((ull)div * 2 + rb) * NS;
        float* outp = (phase == 2) ? (ws + O_GBBN + (ull)div * NS)
                                   : (ws + O_GBB + ((ull)div * 2 + wb) * NS);
        float m, s;
        softmin_1k(Crow, phase ? hb : nullptr, B_LOG2, ie2, qsc, lane, m, s);
        if (lane == 0) {
            float res = -eps * LN2 * (m + log2f(s));
            if (phase == 1) res = 0.5f * (hb[i] + res);
            outp[i] = res;
        }
    }
}

// ---- dist[d] = mean(f_ab_n - f_aa_n) + mean(g_ab_n - g_bb_n) ----
__global__ __launch_bounds__(256)
void reduce_dist(float* __restrict__ ws)
{
    const int d = blockIdx.x;
    const int tix = threadIdx.x;
    float s = 0.0f;
    #pragma unroll
    for (int k = 0; k < 16; k++) {
        const int i = tix + k * 256;
        s += (ws[O_FABN + (ull)d * ND + i] - ws[O_FAAN + (ull)d * ND + i]) * (1.0f / 4096.0f);
    }
    #pragma unroll
    for (int k = 0; k < 4; k++) {
        const int j = tix + k * 256;
        s += (ws[O_GABN + (ull)d * NS + j] - ws[O_GBBN + (ull)d * NS + j]) * (1.0f / 1024.0f);
    }
    s = wave_sum(s);
    __shared__ float red[4];
    const int wid = tix >> 6, lane = tix & 63;
    if (lane == 0) red[wid] = s;
    __syncthreads();
    if (tix == 0) ws[O_DIST + d] = red[0] + red[1] + red[2] + red[3];
}

__global__ void finalize_k(const float* __restrict__ ws, float* __restrict__ out)
{
    const float x = ws[O_DIST + 1] - ws[O_DIST + 0];   // dist2 - dist1
    out[0] = 1.0f / (1.0f + expf(-x));
}

extern "C" void kernel_launch(void* const* d_in, const int* in_sizes, int n_in,
                              void* d_out, int out_size, void* d_ws, size_t ws_size,
                              hipStream_t stream)
{
    if (ws_size < WS_FLOATS * sizeof(float)) return;   // ~105 MB required

    const float* dmat = (const float*)d_in[0];
    const float* s1   = (const float*)d_in[1];
    const float* s2   = (const float*)d_in[2];
    const float* M    = (const float*)d_in[3];
    float* ws  = (float*)d_ws;
    float* out = (float*)d_out;
    unsigned short* uq = (unsigned short*)d_ws;

    float* Mt = ws + O_MT;
    float* xd = ws + O_XD;
    float* x1 = ws + O_X1;
    float* x2 = ws + O_X2;

    // pack raw inputs (K=768) into MFMA fragment order, bf16 hi/mid
    transpose_M_k<<<768, 256, 0, stream>>>(M, Mt);
    pack_bf16_gen<<<256, 256, 0, stream>>>(dmat, uq + P_DH,  uq + P_DM,  24);
    pack_bf16_gen<<<64,  256, 0, stream>>>(s1,   uq + P_S1H, uq + P_S1M, 24);
    pack_bf16_gen<<<64,  256, 0, stream>>>(s2,   uq + P_S2H, uq + P_S2M, 24);
    pack_bf16_gen<<<16,  256, 0, stream>>>(Mt,   uq + P_MTH, uq + P_MTM, 24);
    // projections via MFMA (bf16x3), fp32 outputs
    gemm_proj_mfma<<<dim3(4, 32), 256, 0, stream>>>(uq+P_DH,  uq+P_DM,  uq+P_MTH, uq+P_MTM, xd, 256, 24);
    gemm_proj_mfma<<<dim3(4, 8),  256, 0, stream>>>(uq+P_S1H, uq+P_S1M, uq+P_MTH, uq+P_MTM, x1, 256, 24);
    gemm_proj_mfma<<<dim3(4, 8),  256, 0, stream>>>(uq+P_S2H, uq+P_S2M, uq+P_MTH, uq+P_MTM, x2, 256, 24);
    row_norm<<<4096, 256, 0, stream>>>(xd, ws + O_ND_);
    row_norm<<<1024, 256, 0, stream>>>(x1, ws + O_N1);
    row_norm<<<1024, 256, 0, stream>>>(x2, ws + O_N2);
    colminmax_k<<<96, 256, 0, stream>>>(xd, x1, x2, ws);   // overwrites dead Mt
    eps_k<<<1, 256, 0, stream>>>(ws);
    // pack projected coords (K=256) for cost GEMMs
    pack_bf16_gen<<<256, 256, 0, stream>>>(xd, uq + P_XDH, uq + P_XDM, 8);
    pack_bf16_gen<<<64,  256, 0, stream>>>(x1, uq + P_X1H, uq + P_X1M, 8);
    pack_bf16_gen<<<64,  256, 0, stream>>>(x2, uq + P_X2H, uq + P_X2M, 8);
    // cost matrices via MFMA (bf16x3, 128x64 tile); CT as swapped-operand GEMMs
    const float* qsp = ws + O_QS;
    const float* nd_ = ws + O_ND_;
    const float* n1  = ws + O_N1;
    const float* n2  = ws + O_N2;
    gemm_cost_mfma<<<dim3(64, 32), 256, 0, stream>>>(uq+P_XDH, uq+P_XDM, uq+P_XDH, uq+P_XDM, uq + U_CXX,         nd_, nd_, qsp, 4096);
    gemm_cost_mfma<<<dim3(16, 32), 256, 0, stream>>>(uq+P_XDH, uq+P_XDM, uq+P_X1H, uq+P_X1M, uq + U_CXY,         nd_, n1,  qsp, 1024);
    gemm_cost_mfma<<<dim3(64, 8),  256, 0, stream>>>(uq+P_X1H, uq+P_X1M, uq+P_XDH, uq+P_XDM, uq + U_CYX,         n1,  nd_, qsp, 4096);
    gemm_cost_mfma<<<dim3(16, 32), 256, 0, stream>>>(uq+P_XDH, uq+P_XDM, uq+P_X2H, uq+P_X2M, uq + U_CXY + ND*NS, nd_, n2,  qsp, 1024);
    gemm_cost_mfma<<<dim3(64, 8),  256, 0, stream>>>(uq+P_X2H, uq+P_X2M, uq+P_XDH, uq+P_XDM, uq + U_CYX + ND*NS, n2,  nd_, qsp, 4096);
    gemm_cost_mfma<<<dim3(16, 8),  256, 0, stream>>>(uq+P_X1H, uq+P_X1M, uq+P_X1H, uq+P_X1M, uq + U_CYY,         n1,  n1,  qsp, 1024);
    gemm_cost_mfma<<<dim3(16, 8),  256, 0, stream>>>(uq+P_X2H, uq+P_X2M, uq+P_X2H, uq+P_X2M, uq + U_CYY + NS*NS, n2,  n2,  qsp, 1024);
    // Sinkhorn loop: 51200 uniform 1024-elem waves, multi-launch barriers
    sinkhorn_phase<<<12800, 256, 0, stream>>>(ws, 0, 0);
    for (int t = 0; t < NIT; t++)
        sinkhorn_phase<<<12800, 256, 0, stream>>>(ws, 1, t);
    sinkhorn_phase<<<12800, 256, 0, stream>>>(ws, 2, 36);
    reduce_dist<<<2, 256, 0, stream>>>(ws);
    finalize_k<<<1, 1, 0, stream>>>(ws, out);
}

// Round 13
// 1191.338 us; speedup vs baseline: 1.9300x; 1.0822x over previous
//
#include <hip/hip_runtime.h>
#include <hip/hip_bf16.h>
#include <math.h>

using ull = unsigned long long;
typedef unsigned short u16x8 __attribute__((ext_vector_type(8)));
typedef __attribute__((ext_vector_type(8))) short bf16x8;   // 8 bf16 (4 VGPRs)
typedef __attribute__((ext_vector_type(4))) float f32x4;

// Problem constants
#define ND 4096ull   // n (xd rows)
#define NS 1024ull   // m (s1/s2 rows)
#define DOUT 256ull
#define DIN 768ull
#define NIT 36

// ---- u16 regions (ushort offsets into ws) ----
constexpr ull U_CXX = 0;                 // [ND*ND], shared by both divergences
constexpr ull U_CXY = U_CXX + ND*ND;     // [2][ND*NS]
constexpr ull U_CYX = U_CXY + 2*ND*NS;   // [2][NS*ND] transposed copies
constexpr ull U_CYY = U_CYX + 2*ND*NS;   // [2][NS*NS]
constexpr ull U_TOT = U_CYY + 2*NS*NS;   // ~71.3 MB
// bf16 hi/mid packed fragment buffers for cost GEMMs (K=256)
constexpr ull P_XDH = U_TOT;
constexpr ull P_XDM = P_XDH + ND*DOUT;
constexpr ull P_X1H = P_XDM + ND*DOUT;
constexpr ull P_X1M = P_X1H + NS*DOUT;
constexpr ull P_X2H = P_X1M + NS*DOUT;
constexpr ull P_X2M = P_X2H + NS*DOUT;
// bf16 hi/mid packed fragment buffers for projection GEMMs (K=768)
constexpr ull P_DH  = P_X2M + NS*DOUT;
constexpr ull P_DM  = P_DH + ND*DIN;
constexpr ull P_S1H = P_DM + ND*DIN;
constexpr ull P_S1M = P_S1H + NS*DIN;
constexpr ull P_S2H = P_S1M + NS*DIN;
constexpr ull P_S2M = P_S2H + NS*DIN;
constexpr ull P_MTH = P_S2M + NS*DIN;
constexpr ull P_MTM = P_MTH + DOUT*DIN;
constexpr ull U_END = P_MTM + DOUT*DIN;  // even

// ---- fp32 region (float offsets into ws) ----
constexpr ull O_XD   = U_END / 2;
constexpr ull O_X1   = O_XD + ND*DOUT;
constexpr ull O_X2   = O_X1 + NS*DOUT;
constexpr ull O_MT   = O_X2 + NS*DOUT;       // [DOUT*DIN], dead after Mt pack
constexpr ull O_ND_  = O_MT + DOUT*DIN;
constexpr ull O_N1   = O_ND_ + ND;
constexpr ull O_N2   = O_N1 + NS;
constexpr ull O_FAB  = O_N2 + NS;            // [2 div][2 buf][ND]
constexpr ull O_GAB  = O_FAB + 4*ND;         // [2][2][NS]
constexpr ull O_FAA  = O_GAB + 4*NS;         // [2][2][ND]
constexpr ull O_GBB  = O_FAA + 4*ND;         // [2][2][NS]
constexpr ull O_FABN = O_GBB + 4*NS;         // [2][ND]
constexpr ull O_GABN = O_FABN + 2*ND;        // [2][NS]
constexpr ull O_FAAN = O_GABN + 2*NS;        // [2][ND]
constexpr ull O_GBBN = O_FAAN + 2*ND;        // [2][NS]
constexpr ull O_EPS  = O_GBBN + 2*NS;        // [2][NIT]
constexpr ull O_QS   = O_EPS + 2*NIT;        // [0]=quant scale, [1]=dequant
constexpr ull O_DIST = O_QS + 2;             // [2]
constexpr ull WS_FLOATS = O_DIST + 2;        // ~105 MB total
// diameter partials reuse dead Mt region (after Mt is packed)
constexpr ull O_PMIN = O_MT;                 // [96*256]
constexpr ull O_PMAX = O_MT + 96*256;        // [96*256]

constexpr float LOG2E = 1.4426950408889634f;
constexpr float LN2   = 0.69314718055994531f;
constexpr float A_LOG2 = -12.0f;   // -log2(4096)
constexpr float B_LOG2 = -10.0f;   // -log2(1024)

__device__ __forceinline__ float wave_max(float v) {
    #pragma unroll
    for (int o = 32; o; o >>= 1) v = fmaxf(v, __shfl_xor(v, o));
    return v;
}
__device__ __forceinline__ float wave_sum(float v) {
    #pragma unroll
    for (int o = 32; o; o >>= 1) v += __shfl_xor(v, o);
    return v;
}

__device__ __forceinline__ unsigned short f2bf_rn(float x) {
    union { float f; unsigned u; } v; v.f = x;
    const unsigned r = v.u + 0x7FFFu + ((v.u >> 16) & 1u);
    return (unsigned short)(r >> 16);
}
__device__ __forceinline__ float bf2f(unsigned short b) {
    union { unsigned u; float f; } v; v.u = ((unsigned)b) << 16; return v.f;
}

// ---- transpose M [DIN x DOUT] -> Mt [DOUT x DIN] ----
__global__ __launch_bounds__(256)
void transpose_M_k(const float* __restrict__ M, float* __restrict__ Mt)
{
    int idx = blockIdx.x * 256 + threadIdx.x;
    int r = idx >> 8;
    int c = idx & 255;
    Mt[(size_t)c * DIN + r] = M[idx];
}

// ---- pack fp32 [R][KB*32] -> bf16 hi/mid in MFMA fragment order ----
// slot(p,kb,l,e) = ((p*KB+kb)*64+l)*8+e  holds  X[p*16+(l&15)][kb*32+(l>>4)*8+e]
__global__ __launch_bounds__(256)
void pack_bf16_gen(const float* __restrict__ X,
                   unsigned short* __restrict__ Phi, unsigned short* __restrict__ Pmi,
                   int KB)
{
    const int p = blockIdx.x;
    const int t = threadIdx.x;
    const int K = KB * 32;
    for (int s = t; s < KB * 64; s += 256) {
        const int kb = s >> 6, l = s & 63;
        const int row = p * 16 + (l & 15);
        const int k0 = kb * 32 + ((l >> 4) << 3);
        const float* src = X + (ull)row * K + k0;
        u16x8 hi, mi;
        #pragma unroll
        for (int e = 0; e < 8; e++) {
            const float x = src[e];
            const unsigned short h = f2bf_rn(x);
            hi[e] = h;
            mi[e] = f2bf_rn(x - bf2f(h));
        }
        const ull o = (((ull)p * KB + kb) * 64 + l) * 8;
        *(u16x8*)&Phi[o] = hi;
        *(u16x8*)&Pmi[o] = mi;
    }
}

// ---- MFMA projection GEMM (bf16x3): C[M][256] fp32 = A @ B^T, K = KB*32 ----
__global__ __launch_bounds__(256)
void gemm_proj_mfma(const unsigned short* __restrict__ Ahi, const unsigned short* __restrict__ Ami,
                    const unsigned short* __restrict__ Bhi, const unsigned short* __restrict__ Bmi,
                    float* __restrict__ C, int N, int KB)
{
    const int l = threadIdx.x & 63;
    const int w = threadIdx.x >> 6;
    const int n0 = blockIdx.x * 64, m0 = blockIdx.y * 128;
    const int pA0 = (m0 >> 4) + w * 2;
    const int pB0 = n0 >> 4;
    f32x4 acc[2][4] = {};
    for (int kb = 0; kb < KB; kb++) {
        const ull a0o = (((ull)(pA0 + 0) * KB + kb) * 64 + l) * 8;
        const ull a1o = (((ull)(pA0 + 1) * KB + kb) * 64 + l) * 8;
        const bf16x8 aH0 = *(const bf16x8*)&Ahi[a0o];
        const bf16x8 aM0 = *(const bf16x8*)&Ami[a0o];
        const bf16x8 aH1 = *(const bf16x8*)&Ahi[a1o];
        const bf16x8 aM1 = *(const bf16x8*)&Ami[a1o];
        #pragma unroll
        for (int j = 0; j < 4; j++) {
            const ull bo = (((ull)(pB0 + j) * KB + kb) * 64 + l) * 8;
            const bf16x8 bH = *(const bf16x8*)&Bhi[bo];
            const bf16x8 bM = *(const bf16x8*)&Bmi[bo];
            acc[0][j] = __builtin_amdgcn_mfma_f32_16x16x32_bf16(aH0, bH, acc[0][j], 0, 0, 0);
            acc[0][j] = __builtin_amdgcn_mfma_f32_16x16x32_bf16(aH0, bM, acc[0][j], 0, 0, 0);
            acc[0][j] = __builtin_amdgcn_mfma_f32_16x16x32_bf16(aM0, bH, acc[0][j], 0, 0, 0);
            acc[1][j] = __builtin_amdgcn_mfma_f32_16x16x32_bf16(aH1, bH, acc[1][j], 0, 0, 0);
            acc[1][j] = __builtin_amdgcn_mfma_f32_16x16x32_bf16(aH1, bM, acc[1][j], 0, 0, 0);
            acc[1][j] = __builtin_amdgcn_mfma_f32_16x16x32_bf16(aM1, bH, acc[1][j], 0, 0, 0);
        }
    }
    const int col = l & 15;
    #pragma unroll
    for (int i = 0; i < 2; i++) {
        const int row0 = m0 + w * 32 + i * 16 + ((l >> 4) << 2);
        #pragma unroll
        for (int r = 0; r < 4; r++) {
            const ull rowb = (ull)(row0 + r) * N + n0;
            #pragma unroll
            for (int j = 0; j < 4; j++)
                C[rowb + j * 16 + col] = acc[i][j][r];
        }
    }
}

// ---- MFMA cost GEMM (bf16x3 split), 128x64 block tile, 2 A-panels/wave ----
__device__ __forceinline__ unsigned int quant16(float c, float s) {
    return __float2uint_rn(fminf(c * s, 65535.0f));
}

__global__ __launch_bounds__(256)
void gemm_cost_mfma(const unsigned short* __restrict__ Ahi, const unsigned short* __restrict__ Ami,
                    const unsigned short* __restrict__ Bhi, const unsigned short* __restrict__ Bmi,
                    unsigned short* __restrict__ C,
                    const float* __restrict__ na, const float* __restrict__ nb,
                    const float* __restrict__ qsp, int N)
{
    const int l = threadIdx.x & 63;
    const int w = threadIdx.x >> 6;
    const int n0 = blockIdx.x * 64, m0 = blockIdx.y * 128;
    const int pA0 = (m0 >> 4) + w * 2;   // 2 A panels per wave (32 rows)
    const int pB0 = n0 >> 4;
    f32x4 acc[2][4] = {};
    #pragma unroll
    for (int kb = 0; kb < 8; kb++) {
        const ull a0o = (((ull)(pA0 + 0) * 8 + kb) * 64 + l) * 8;
        const ull a1o = (((ull)(pA0 + 1) * 8 + kb) * 64 + l) * 8;
        const bf16x8 aH0 = *(const bf16x8*)&Ahi[a0o];
        const bf16x8 aM0 = *(const bf16x8*)&Ami[a0o];
        const bf16x8 aH1 = *(const bf16x8*)&Ahi[a1o];
        const bf16x8 aM1 = *(const bf16x8*)&Ami[a1o];
        #pragma unroll
        for (int j = 0; j < 4; j++) {
            const ull bo = (((ull)(pB0 + j) * 8 + kb) * 64 + l) * 8;
            const bf16x8 bH = *(const bf16x8*)&Bhi[bo];
            const bf16x8 bM = *(const bf16x8*)&Bmi[bo];
            acc[0][j] = __builtin_amdgcn_mfma_f32_16x16x32_bf16(aH0, bH, acc[0][j], 0, 0, 0);
            acc[0][j] = __builtin_amdgcn_mfma_f32_16x16x32_bf16(aH0, bM, acc[0][j], 0, 0, 0);
            acc[0][j] = __builtin_amdgcn_mfma_f32_16x16x32_bf16(aM0, bH, acc[0][j], 0, 0, 0);
            acc[1][j] = __builtin_amdgcn_mfma_f32_16x16x32_bf16(aH1, bH, acc[1][j], 0, 0, 0);
            acc[1][j] = __builtin_amdgcn_mfma_f32_16x16x32_bf16(aH1, bM, acc[1][j], 0, 0, 0);
            acc[1][j] = __builtin_amdgcn_mfma_f32_16x16x32_bf16(aM1, bH, acc[1][j], 0, 0, 0);
        }
    }
    const float s = qsp[0];
    const int col = l & 15;
    float nbj[4];
    #pragma unroll
    for (int j = 0; j < 4; j++) nbj[j] = nb[n0 + j * 16 + col];
    #pragma unroll
    for (int i = 0; i < 2; i++) {
        const int row0 = m0 + w * 32 + i * 16 + ((l >> 4) << 2);
        #pragma unroll
        for (int r = 0; r < 4; r++) {
            const float nar = na[row0 + r];
            const ull rowb = (ull)(row0 + r) * N + n0;
            #pragma unroll
            for (int j = 0; j < 4; j++)
                C[rowb + j * 16 + col] =
                    (unsigned short)quant16(0.5f * fmaxf(nar + nbj[j] - 2.0f * acc[i][j][r], 0.0f), s);
        }
    }
}

// ---- row squared-norms ----
__global__ __launch_bounds__(256)
void row_norm(const float* __restrict__ x, float* __restrict__ o)
{
    const int i = blockIdx.x;
    const float v = x[(size_t)i * DOUT + threadIdx.x];
    float s = wave_sum(v * v);
    __shared__ float red[4];
    const int wid = threadIdx.x >> 6, lane = threadIdx.x & 63;
    if (lane == 0) red[wid] = s;
    __syncthreads();
    if (threadIdx.x == 0) o[i] = red[0] + red[1] + red[2] + red[3];
}

// ---- per-column min/max partials ----
__global__ __launch_bounds__(256)
void colminmax_k(const float* __restrict__ xd, const float* __restrict__ x1,
                 const float* __restrict__ x2, float* __restrict__ ws)
{
    const int b = blockIdx.x, c = threadIdx.x;
    const float* src; int r0;
    if (b < 64)      { src = xd; r0 = b * 64; }
    else if (b < 80) { src = x1; r0 = (b - 64) * 64; }
    else             { src = x2; r0 = (b - 80) * 64; }
    float mn = 3.4e38f, mx = -3.4e38f;
    for (int r = 0; r < 64; r++) {
        const float v = src[(size_t)(r0 + r) * DOUT + c];
        mn = fminf(mn, v); mx = fmaxf(mx, v);
    }
    ws[O_PMIN + (ull)b * 256 + c] = mn;
    ws[O_PMAX + (ull)b * 256 + c] = mx;
}

// ---- partials -> diam -> eps schedule + quant scale ----
__global__ __launch_bounds__(256)
void eps_k(float* __restrict__ ws)
{
    const int c = threadIdx.x;
    const float* pmin = ws + O_PMIN;
    const float* pmax = ws + O_PMAX;
    float mnd = 3.4e38f, mxd = -3.4e38f;
    float mn1 = 3.4e38f, mx1 = -3.4e38f;
    float mn2 = 3.4e38f, mx2 = -3.4e38f;
    for (int b = 0;  b < 64; b++) { mnd = fminf(mnd, pmin[b*256+c]); mxd = fmaxf(mxd, pmax[b*256+c]); }
    for (int b = 64; b < 80; b++) { mn1 = fminf(mn1, pmin[b*256+c]); mx1 = fmaxf(mx1, pmax[b*256+c]); }
    for (int b = 80; b < 96; b++) { mn2 = fminf(mn2, pmin[b*256+c]); mx2 = fmaxf(mx2, pmax[b*256+c]); }
    const float d1 = fmaxf(mxd, mx1) - fminf(mnd, mn1);
    const float d2 = fmaxf(mxd, mx2) - fminf(mnd, mn2);
    float s1 = wave_sum(d1 * d1);
    float s2 = wave_sum(d2 * d2);
    __shared__ float r1[4], r2[4];
    const int wid = c >> 6, lane = c & 63;
    if (lane == 0) { r1[wid] = s1; r2[wid] = s2; }
    __syncthreads();
    if (c == 0) {
        const float d1s = r1[0]+r1[1]+r1[2]+r1[3];
        const float d2s = r2[0]+r2[1]+r2[2]+r2[3];
        const float cb = 0.5f * fmaxf(d1s, d2s) * 1.02f + 1.0f;
        ws[O_QS]     = 65535.0f / cb;
        ws[O_QS + 1] = cb / 65535.0f;
    }
    if (c < 2 * NIT) {
        const int div = c / NIT, tt = c % NIT;
        const float ss = div ? (r2[0]+r2[1]+r2[2]+r2[3]) : (r1[0]+r1[1]+r1[2]+r1[3]);
        const float diam = sqrtf(ss) + 1e-6f;
        const float sc = fmaxf(0.5f, diam * powf(0.8f, (float)tt));
        ws[O_EPS + (ull)div * NIT + tt] = sc * sc;
    }
}

// ---- 1024-element softmin segment: returns wave-reduced partial (m, s) ----
__device__ __forceinline__ void softmin_1k(
    const unsigned short* __restrict__ Cseg, const float* __restrict__ hseg,
    float hc2, float ie2, float qsc, int lane, float& mO, float& sO)
{
    float v[16];
    #pragma unroll
    for (int c = 0; c < 2; c++) {
        const int off = c * 512 + lane * 8;
        const u16x8 q = *(const u16x8*)&Cseg[off];
        if (hseg) {
            const float4 ha = *(const float4*)&hseg[off];
            const float4 hb = *(const float4*)&hseg[off + 4];
            const float hv[8] = {ha.x, ha.y, ha.z, ha.w, hb.x, hb.y, hb.z, hb.w};
            #pragma unroll
            for (int e = 0; e < 8; e++)
                v[c*8 + e] = fmaf((float)q[e], qsc, fmaf(hv[e], ie2, hc2));
        } else {
            #pragma unroll
            for (int e = 0; e < 8; e++)
                v[c*8 + e] = fmaf((float)q[e], qsc, hc2);
        }
    }
    float m = v[0];
    #pragma unroll
    for (int k = 1; k < 16; k++) m = fmaxf(m, v[k]);
    m = wave_max(m);
    float s = 0.0f;
    #pragma unroll
    for (int k = 0; k < 16; k++) s += exp2f(v[k] - m);
    sO = wave_sum(s);
    mO = m;
}

// ---- fused Sinkhorn step: 34816 uniform waves (8704 blocks x 4) ----
// Every wave reads exactly 1024 C elements; faa waves run BOTH divergences'
// exp-chains on ONE C_xx segment read (bytes 100 -> 68 MB/dispatch).
// block map:
//  [0,2048)     ft   4 short rows/block (wave w -> row), div = b>>10
//  [2048,4096)  gt   1 long row split across 4 waves, div = (b-2048)>>10
//  [4096,8192)  faa  1 C_xx row split across 4 waves, both divs per wave
//  [8192,8704)  g_bb 4 short rows/block, div = (b-8192)>>8
__global__ __launch_bounds__(256)
void sinkhorn_phase(float* __restrict__ ws, int phase, int t)
{
    __shared__ float mS[8], sS[8];
    const unsigned short* uq = (const unsigned short*)ws;
    const int wid = threadIdx.x >> 6, lane = threadIdx.x & 63;
    const float qs = ws[O_QS + 1];
    int rb, wb;
    if (phase == 0) { rb = 0; wb = 0; }
    else { rb = t & 1; wb = rb ^ 1; }   // phase 2 passes t=36 -> rb=0
    const int b = blockIdx.x;

    if (b < 2048) {                       // ft -> f_ab : 4 rows, 1 per wave
        const int div = b >> 10;
        const int i = ((b & 1023) << 2) + wid;
        const float eps = (phase == 2) ? 0.25f : ws[O_EPS + (ull)div * NIT + t];
        const float ie2 = LOG2E / eps, qsc = -qs * ie2;
        const unsigned short* Crow = uq + U_CXY + (ull)div * ND * NS + (ull)i * NS;
        const float* h    = phase ? (ws + O_GAB + ((ull)div * 2 + rb) * NS) : nullptr;
        const float* self = ws + O_FAB + ((ull)div * 2 + rb) * ND;
        float* outp = (phase == 2) ? (ws + O_FABN + (ull)div * ND)
                                   : (ws + O_FAB + ((ull)div * 2 + wb) * ND);
        float m, s;
        softmin_1k(Crow, h, B_LOG2, ie2, qsc, lane, m, s);
        if (lane == 0) {
            float res = -eps * LN2 * (m + log2f(s));
            if (phase == 1) res = 0.5f * (self[i] + res);
            outp[i] = res;
        }
    } else if (b < 4096) {                // gt -> g_ab : 1 row / 4 waves
        const int q = b - 2048, div = q >> 10, j = q & 1023;
        const float eps = (phase == 2) ? 0.25f : ws[O_EPS + (ull)div * NIT + t];
        const float ie2 = LOG2E / eps, qsc = -qs * ie2;
        const unsigned short* Cseg = uq + U_CYX + (ull)div * ND * NS + (ull)j * ND + wid * 1024;
        const float* h    = phase ? (ws + O_FAB + ((ull)div * 2 + rb) * ND + wid * 1024) : nullptr;
        const float* self = ws + O_GAB + ((ull)div * 2 + rb) * NS;
        float* outp = (phase == 2) ? (ws + O_GABN + (ull)div * NS)
                                   : (ws + O_GAB + ((ull)div * 2 + wb) * NS);
        float m, s;
        softmin_1k(Cseg, h, A_LOG2, ie2, qsc, lane, m, s);
        if (lane == 0) { mS[wid] = m; sS[wid] = s; }
        __syncthreads();
        if (threadIdx.x == 0) {
            const float m0 = fmaxf(fmaxf(mS[0], mS[1]), fmaxf(mS[2], mS[3]));
            const float st = sS[0]*exp2f(mS[0]-m0) + sS[1]*exp2f(mS[1]-m0)
                           + sS[2]*exp2f(mS[2]-m0) + sS[3]*exp2f(mS[3]-m0);
            float res = -eps * LN2 * (m0 + log2f(st));
            if (phase == 1) res = 0.5f * (self[j] + res);
            outp[j] = res;
        }
    } else if (b < 8192) {                // f_aa : 1 row / 4 waves, BOTH divs
        const int i = b - 4096;
        const float eps0 = (phase == 2) ? 0.25f : ws[O_EPS + t];
        const float eps1 = (phase == 2) ? 0.25f : ws[O_EPS + NIT + t];
        const float ie0 = LOG2E / eps0, qs0 = -qs * ie0;
        const float ie1 = LOG2E / eps1, qs1 = -qs * ie1;
        const unsigned short* Cseg = uq + U_CXX + (ull)i * ND + wid * 1024;
        const float* h0b = ws + O_FAA + (ull)rb * ND;
        const float* h1b = ws + O_FAA + (2ull + rb) * ND;
        float* out0 = (phase == 2) ? (ws + O_FAAN)      : (ws + O_FAA + (ull)wb * ND);
        float* out1 = (phase == 2) ? (ws + O_FAAN + ND) : (ws + O_FAA + (2ull + wb) * ND);
        float v0[16], v1[16];
        #pragma unroll
        for (int c = 0; c < 2; c++) {
            const int off = c * 512 + lane * 8;
            const u16x8 q = *(const u16x8*)&Cseg[off];
            float cq[8];
            #pragma unroll
            for (int e = 0; e < 8; e++) cq[e] = (float)q[e];
            if (phase) {
                const int go = wid * 1024 + off;
                const float4 a0 = *(const float4*)&h0b[go];
                const float4 b0 = *(const float4*)&h0b[go + 4];
                const float4 a1 = *(const float4*)&h1b[go];
                const float4 b1 = *(const float4*)&h1b[go + 4];
                const float h0v[8] = {a0.x, a0.y, a0.z, a0.w, b0.x, b0.y, b0.z, b0.w};
                const float h1v[8] = {a1.x, a1.y, a1.z, a1.w, b1.x, b1.y, b1.z, b1.w};
                #pragma unroll
                for (int e = 0; e < 8; e++) {
                    v0[c*8 + e] = fmaf(cq[e], qs0, fmaf(h0v[e], ie0, A_LOG2));
                    v1[c*8 + e] = fmaf(cq[e], qs1, fmaf(h1v[e], ie1, A_LOG2));
                }
            } else {
                #pragma unroll
                for (int e = 0; e < 8; e++) {
                    v0[c*8 + e] = fmaf(cq[e], qs0, A_LOG2);
                    v1[c*8 + e] = fmaf(cq[e], qs1, A_LOG2);
                }
            }
        }
        float m0 = v0[0], m1 = v1[0];
        #pragma unroll
        for (int k = 1; k < 16; k++) { m0 = fmaxf(m0, v0[k]); m1 = fmaxf(m1, v1[k]); }
        m0 = wave_max(m0); m1 = wave_max(m1);
        float s0 = 0.0f, s1 = 0.0f;
        #pragma unroll
        for (int k = 0; k < 16; k++) { s0 += exp2f(v0[k] - m0); s1 += exp2f(v1[k] - m1); }
        s0 = wave_sum(s0); s1 = wave_sum(s1);
        if (lane == 0) { mS[wid] = m0; sS[wid] = s0; mS[4 + wid] = m1; sS[4 + wid] = s1; }
        __syncthreads();
        if (threadIdx.x == 0) {
            const float ma = fmaxf(fmaxf(mS[0], mS[1]), fmaxf(mS[2], mS[3]));
            const float sa = sS[0]*exp2f(mS[0]-ma) + sS[1]*exp2f(mS[1]-ma)
                           + sS[2]*exp2f(mS[2]-ma) + sS[3]*exp2f(mS[3]-ma);
            float r0 = -eps0 * LN2 * (ma + log2f(sa));
            if (phase == 1) r0 = 0.5f * (h0b[i] + r0);
            out0[i] = r0;
            const float mb = fmaxf(fmaxf(mS[4], mS[5]), fmaxf(mS[6], mS[7]));
            const float sb = sS[4]*exp2f(mS[4]-mb) + sS[5]*exp2f(mS[5]-mb)
                           + sS[6]*exp2f(mS[6]-mb) + sS[7]*exp2f(mS[7]-mb);
            float r1 = -eps1 * LN2 * (mb + log2f(sb));
            if (phase == 1) r1 = 0.5f * (h1b[i] + r1);
            out1[i] = r1;
        }
    } else {                              // g_bb : 4 rows, 1 per wave
        const int q = b - 8192, div = q >> 8;
        const int i = ((q & 255) << 2) + wid;
        const float eps = (phase == 2) ? 0.25f : ws[O_EPS + (ull)div * NIT + t];
        const float ie2 = LOG2E / eps, qsc = -qs * ie2;
        const unsigned short* Crow = uq + U_CYY + (ull)div * NS * NS + (ull)i * NS;
        const float* hb = ws + O_GBB + ((ull)div * 2 + rb) * NS;
        float* outp = (phase == 2) ? (ws + O_GBBN + (ull)div * NS)
                                   : (ws + O_GBB + ((ull)div * 2 + wb) * NS);
        float m, s;
        softmin_1k(Crow, phase ? hb : nullptr, B_LOG2, ie2, qsc, lane, m, s);
        if (lane == 0) {
            float res = -eps * LN2 * (m + log2f(s));
            if (phase == 1) res = 0.5f * (hb[i] + res);
            outp[i] = res;
        }
    }
}

// ---- dist[d] = mean(f_ab_n - f_aa_n) + mean(g_ab_n - g_bb_n) ----
__global__ __launch_bounds__(256)
void reduce_dist(float* __restrict__ ws)
{
    const int d = blockIdx.x;
    const int tix = threadIdx.x;
    float s = 0.0f;
    #pragma unroll
    for (int k = 0; k < 16; k++) {
        const int i = tix + k * 256;
        s += (ws[O_FABN + (ull)d * ND + i] - ws[O_FAAN + (ull)d * ND + i]) * (1.0f / 4096.0f);
    }
    #pragma unroll
    for (int k = 0; k < 4; k++) {
        const int j = tix + k * 256;
        s += (ws[O_GABN + (ull)d * NS + j] - ws[O_GBBN + (ull)d * NS + j]) * (1.0f / 1024.0f);
    }
    s = wave_sum(s);
    __shared__ float red[4];
    const int wid = tix >> 6, lane = tix & 63;
    if (lane == 0) red[wid] = s;
    __syncthreads();
    if (tix == 0) ws[O_DIST + d] = red[0] + red[1] + red[2] + red[3];
}

__global__ void finalize_k(const float* __restrict__ ws, float* __restrict__ out)
{
    const float x = ws[O_DIST + 1] - ws[O_DIST + 0];   // dist2 - dist1
    out[0] = 1.0f / (1.0f + expf(-x));
}

extern "C" void kernel_launch(void* const* d_in, const int* in_sizes, int n_in,
                              void* d_out, int out_size, void* d_ws, size_t ws_size,
                              hipStream_t stream)
{
    if (ws_size < WS_FLOATS * sizeof(float)) return;   // ~105 MB required

    const float* dmat = (const float*)d_in[0];
    const float* s1   = (const float*)d_in[1];
    const float* s2   = (const float*)d_in[2];
    const float* M    = (const float*)d_in[3];
    float* ws  = (float*)d_ws;
    float* out = (float*)d_out;
    unsigned short* uq = (unsigned short*)d_ws;

    float* Mt = ws + O_MT;
    float* xd = ws + O_XD;
    float* x1 = ws + O_X1;
    float* x2 = ws + O_X2;

    // pack raw inputs (K=768) into MFMA fragment order, bf16 hi/mid
    transpose_M_k<<<768, 256, 0, stream>>>(M, Mt);
    pack_bf16_gen<<<256, 256, 0, stream>>>(dmat, uq + P_DH,  uq + P_DM,  24);
    pack_bf16_gen<<<64,  256, 0, stream>>>(s1,   uq + P_S1H, uq + P_S1M, 24);
    pack_bf16_gen<<<64,  256, 0, stream>>>(s2,   uq + P_S2H, uq + P_S2M, 24);
    pack_bf16_gen<<<16,  256, 0, stream>>>(Mt,   uq + P_MTH, uq + P_MTM, 24);
    // projections via MFMA (bf16x3), fp32 outputs
    gemm_proj_mfma<<<dim3(4, 32), 256, 0, stream>>>(uq+P_DH,  uq+P_DM,  uq+P_MTH, uq+P_MTM, xd, 256, 24);
    gemm_proj_mfma<<<dim3(4, 8),  256, 0, stream>>>(uq+P_S1H, uq+P_S1M, uq+P_MTH, uq+P_MTM, x1, 256, 24);
    gemm_proj_mfma<<<dim3(4, 8),  256, 0, stream>>>(uq+P_S2H, uq+P_S2M, uq+P_MTH, uq+P_MTM, x2, 256, 24);
    row_norm<<<4096, 256, 0, stream>>>(xd, ws + O_ND_);
    row_norm<<<1024, 256, 0, stream>>>(x1, ws + O_N1);
    row_norm<<<1024, 256, 0, stream>>>(x2, ws + O_N2);
    colminmax_k<<<96, 256, 0, stream>>>(xd, x1, x2, ws);   // overwrites dead Mt
    eps_k<<<1, 256, 0, stream>>>(ws);
    // pack projected coords (K=256) for cost GEMMs
    pack_bf16_gen<<<256, 256, 0, stream>>>(xd, uq + P_XDH, uq + P_XDM, 8);
    pack_bf16_gen<<<64,  256, 0, stream>>>(x1, uq + P_X1H, uq + P_X1M, 8);
    pack_bf16_gen<<<64,  256, 0, stream>>>(x2, uq + P_X2H, uq + P_X2M, 8);
    // cost matrices via MFMA (bf16x3, 128x64 tile); CT as swapped-operand GEMMs
    const float* qsp = ws + O_QS;
    const float* nd_ = ws + O_ND_;
    const float* n1  = ws + O_N1;
    const float* n2  = ws + O_N2;
    gemm_cost_mfma<<<dim3(64, 32), 256, 0, stream>>>(uq+P_XDH, uq+P_XDM, uq+P_XDH, uq+P_XDM, uq + U_CXX,         nd_, nd_, qsp, 4096);
    gemm_cost_mfma<<<dim3(16, 32), 256, 0, stream>>>(uq+P_XDH, uq+P_XDM, uq+P_X1H, uq+P_X1M, uq + U_CXY,         nd_, n1,  qsp, 1024);
    gemm_cost_mfma<<<dim3(64, 8),  256, 0, stream>>>(uq+P_X1H, uq+P_X1M, uq+P_XDH, uq+P_XDM, uq + U_CYX,         n1,  nd_, qsp, 4096);
    gemm_cost_mfma<<<dim3(16, 32), 256, 0, stream>>>(uq+P_XDH, uq+P_XDM, uq+P_X2H, uq+P_X2M, uq + U_CXY + ND*NS, nd_, n2,  qsp, 1024);
    gemm_cost_mfma<<<dim3(64, 8),  256, 0, stream>>>(uq+P_X2H, uq+P_X2M, uq+P_XDH, uq+P_XDM, uq + U_CYX + ND*NS, n2,  nd_, qsp, 4096);
    gemm_cost_mfma<<<dim3(16, 8),  256, 0, stream>>>(uq+P_X1H, uq+P_X1M, uq+P_X1H, uq+P_X1M, uq + U_CYY,         n1,  n1,  qsp, 1024);
    gemm_cost_mfma<<<dim3(16, 8),  256, 0, stream>>>(uq+P_X2H, uq+P_X2M, uq+P_X2H, uq+P_X2M, uq + U_CYY + NS*NS, n2,  n2,  qsp, 1024);
    // Sinkhorn loop: 34816 uniform waves, fused-faa, multi-launch barriers
    sinkhorn_phase<<<8704, 256, 0, stream>>>(ws, 0, 0);
    for (int t = 0; t < NIT; t++)
        sinkhorn_phase<<<8704, 256, 0, stream>>>(ws, 1, t);
    sinkhorn_phase<<<8704, 256, 0, stream>>>(ws, 2, 36);
    reduce_dist<<<2, 256, 0, stream>>>(ws);
    finalize_k<<<1, 1, 0, stream>>>(ws, out);
}